// Round 1
// baseline (2109.053 us; speedup 1.0000x reference)
//
#include <hip/hip_runtime.h>

#define C_DIM 256
#define NHEAD 8
#define DH 32
#define NWIN 64      // Nv
#define HWTOK 256    // hw
#define NTOK 32768   // B * Nv * hw
#define PETOK 16384  // Nv * hw
#define DFF_DIM 1024
#define LN_EPS 1e-5f

// ---------------- rel-pos MLP: rel[hw][C] ----------------
__global__ void rel_pe_kernel(const float* __restrict__ relW1, const float* __restrict__ relb1,
                              const float* __restrict__ relW2, const float* __restrict__ relb2,
                              float* __restrict__ rel) {
    __shared__ float hid[64];
    int t = blockIdx.x;            // 0..255
    int ty = t >> 4, tx = t & 15;
    float cx = tx * (1.0f / 15.0f);
    float cy = ty * (1.0f / 15.0f);
    int tid = threadIdx.x;         // 0..255 = c
    if (tid < 64) {
        float h = relW1[tid * 2 + 0] * cx + relW1[tid * 2 + 1] * cy + relb1[tid];
        hid[tid] = fmaxf(h, 0.0f);
    }
    __syncthreads();
    float acc = relb2[tid];
    #pragma unroll
    for (int j = 0; j < 64; ++j) acc = fmaf(hid[j], relW2[tid * 64 + j], acc);
    rel[t * C_DIM + tid] = acc;
}

// ---------------- pe[v][t][c] = glob windowed + rel ----------------
__global__ void build_pe_kernel(const float* __restrict__ glob, const float* __restrict__ rel,
                                float* __restrict__ pe) {
    int vt = blockIdx.x;                 // v*256 + t
    int v = vt >> 8, t = vt & 255;
    int i = v >> 3, j = v & 7;
    int ty = t >> 4, tx = t & 15;
    int c = threadIdx.x;
    int gidx = c * 16384 + (i * 16 + ty) * 128 + (j * 16 + tx);
    pe[vt * C_DIM + c] = glob[gidx] + rel[t * C_DIM + c];
}

// ---------------- window partition: X[tok][c] ----------------
__global__ void window_kernel(const float* __restrict__ backbone, float* __restrict__ X) {
    int tok = blockIdx.x;                // b*16384 + v*256 + t
    int b = tok >> 14;
    int vt = tok & 16383;
    int v = vt >> 8, t = vt & 255;
    int i = v >> 3, j = v & 7, ty = t >> 4, tx = t & 15;
    int c = threadIdx.x;
    X[tok * C_DIM + c] = backbone[b * 4194304 + c * 16384 + (i * 16 + ty) * 128 + (j * 16 + tx)];
}

// ---------------- generic tiled GEMM: C = A * W^T + bias (opt relu, opt +pe on A) ----------------
// A: [M x K] rowmajor with leading dim lda (row index is the GLOBAL token index if pe != null)
// W: [N x K] rowmajor.  Cout: [M x N] with leading dim ldc. All dims multiples of 64/16.
__global__ __launch_bounds__(256) void gemm_kernel(
        const float* __restrict__ A, int lda, const float* __restrict__ pe,
        const float* __restrict__ W, const float* __restrict__ bias,
        float* __restrict__ Cout, int ldc, int K, int relu) {
    __shared__ float As[16][64];
    __shared__ float Bs[16][64];
    int m0 = blockIdx.y * 64;
    int n0 = blockIdx.x * 64;
    int tid = threadIdx.x;
    int tx = tid & 15, ty = tid >> 4;
    int loadRow = tid >> 2;          // 0..63
    int loadK = (tid & 3) * 4;       // 0,4,8,12
    float acc[4][4] = {};
    for (int k0 = 0; k0 < K; k0 += 16) {
        float4 av = *(const float4*)&A[(m0 + loadRow) * lda + k0 + loadK];
        if (pe) {
            const float4 pv = *(const float4*)&pe[((m0 + loadRow) & 16383) * C_DIM + k0 + loadK];
            av.x += pv.x; av.y += pv.y; av.z += pv.z; av.w += pv.w;
        }
        As[loadK + 0][loadRow] = av.x;
        As[loadK + 1][loadRow] = av.y;
        As[loadK + 2][loadRow] = av.z;
        As[loadK + 3][loadRow] = av.w;
        const float4 bv = *(const float4*)&W[(n0 + loadRow) * K + k0 + loadK];
        Bs[loadK + 0][loadRow] = bv.x;
        Bs[loadK + 1][loadRow] = bv.y;
        Bs[loadK + 2][loadRow] = bv.z;
        Bs[loadK + 3][loadRow] = bv.w;
        __syncthreads();
        #pragma unroll
        for (int kk = 0; kk < 16; ++kk) {
            const float4 a4 = *(const float4*)&As[kk][ty * 4];
            const float4 b4 = *(const float4*)&Bs[kk][tx * 4];
            const float ar[4] = {a4.x, a4.y, a4.z, a4.w};
            const float br[4] = {b4.x, b4.y, b4.z, b4.w};
            #pragma unroll
            for (int i = 0; i < 4; ++i)
                #pragma unroll
                for (int j = 0; j < 4; ++j)
                    acc[i][j] = fmaf(ar[i], br[j], acc[i][j]);
        }
        __syncthreads();
    }
    const float4 bb = *(const float4*)&bias[n0 + tx * 4];
    const float br[4] = {bb.x, bb.y, bb.z, bb.w};
    #pragma unroll
    for (int i = 0; i < 4; ++i) {
        int m = m0 + ty * 4 + i;
        float o[4];
        #pragma unroll
        for (int j = 0; j < 4; ++j) {
            o[j] = acc[i][j] + br[j];
            if (relu) o[j] = fmaxf(o[j], 0.0f);
        }
        float4 ov = {o[0], o[1], o[2], o[3]};
        *(float4*)&Cout[m * ldc + n0 + tx * 4] = ov;
    }
}

// ---------------- attention (online softmax), O written in-place over Q half ----------------
// QK: [NTOK x 512] (cols 0..255 = Q, 256..511 = K proj). V: [NTOK x 256].
// tok(bat,row) = (bat/perB)*16384 + (bat%perB)*innerStride + row*seqStride
__global__ void attn_kernel(const float* __restrict__ QK, const float* __restrict__ V,
                            float* __restrict__ O,
                            int S, int perB, int innerStride, int seqStride) {
    extern __shared__ float sm[];
    float* Ks = sm;                  // [S][33]
    float* Vs = sm + S * 33;         // [S][33]
    int bat = blockIdx.x / NHEAD;
    int head = blockIdx.x % NHEAD;
    int b = bat / perB, r = bat % perB;
    int base = b * PETOK + r * innerStride;
    int row = threadIdx.x;           // 0..S-1
    int tok = base + row * seqStride;

    const float* kp = &QK[tok * 512 + 256 + head * DH];
    const float* vp = &V[tok * C_DIM + head * DH];
    #pragma unroll
    for (int d = 0; d < DH; ++d) {
        Ks[row * 33 + d] = kp[d];
        Vs[row * 33 + d] = vp[d];
    }
    float q[DH];
    const float* qp = &QK[tok * 512 + head * DH];
    #pragma unroll
    for (int d = 0; d < DH; d += 4) {
        const float4 qv = *(const float4*)&qp[d];
        q[d] = qv.x; q[d + 1] = qv.y; q[d + 2] = qv.z; q[d + 3] = qv.w;
    }
    __syncthreads();

    const float scale = 0.17677669529663687f;   // 1/sqrt(32)
    float m = -1e30f, l = 0.0f;
    float acc[DH];
    #pragma unroll
    for (int d = 0; d < DH; ++d) acc[d] = 0.0f;
    for (int k = 0; k < S; ++k) {
        float s = 0.0f;
        #pragma unroll
        for (int d = 0; d < DH; ++d) s = fmaf(q[d], Ks[k * 33 + d], s);
        s *= scale;
        float nm = fmaxf(m, s);
        float corr = __expf(m - nm);
        float p = __expf(s - nm);
        l = l * corr + p;
        #pragma unroll
        for (int d = 0; d < DH; ++d) acc[d] = fmaf(acc[d], corr, p * Vs[k * 33 + d]);
        m = nm;
    }
    float inv = 1.0f / l;
    float* op = &O[tok * 512 + head * DH];
    #pragma unroll
    for (int d = 0; d < DH; ++d) op[d] = acc[d] * inv;
}

// ---------------- residual + LayerNorm (in-place on X): X = LN(X + Y) * g + b ----------------
__global__ __launch_bounds__(256) void ln_kernel(float* __restrict__ X, const float* __restrict__ Y,
                                                 const float* __restrict__ g, const float* __restrict__ be,
                                                 int tokBase) {
    int tok = tokBase + blockIdx.x * 4 + (threadIdx.x >> 6);
    int lane = threadIdx.x & 63;
    float4 x = *(float4*)&X[tok * C_DIM + lane * 4];
    const float4 y = *(const float4*)&Y[tok * C_DIM + lane * 4];
    float v0 = x.x + y.x, v1 = x.y + y.y, v2 = x.z + y.z, v3 = x.w + y.w;
    float s = v0 + v1 + v2 + v3;
    float ss = v0 * v0 + v1 * v1 + v2 * v2 + v3 * v3;
    #pragma unroll
    for (int off = 32; off; off >>= 1) {
        s += __shfl_xor(s, off, 64);
        ss += __shfl_xor(ss, off, 64);
    }
    float mean = s * (1.0f / 256.0f);
    float var = ss * (1.0f / 256.0f) - mean * mean;
    float inv = rsqrtf(var + LN_EPS);
    const float4 gv = *(const float4*)&g[lane * 4];
    const float4 bv = *(const float4*)&be[lane * 4];
    float4 o;
    o.x = (v0 - mean) * inv * gv.x + bv.x;
    o.y = (v1 - mean) * inv * gv.y + bv.y;
    o.z = (v2 - mean) * inv * gv.z + bv.z;
    o.w = (v3 - mean) * inv * gv.w + bv.w;
    *(float4*)&X[tok * C_DIM + lane * 4] = o;
}

// ---------------- scatter back + residual: out = backbone + windows^-1(X) ----------------
__global__ void scatter_kernel(const float* __restrict__ backbone, const float* __restrict__ X,
                               float* __restrict__ out) {
    int tok = blockIdx.x;
    int b = tok >> 14;
    int vt = tok & 16383;
    int v = vt >> 8, t = vt & 255;
    int i = v >> 3, j = v & 7, ty = t >> 4, tx = t & 15;
    int c = threadIdx.x;
    int gi = b * 4194304 + c * 16384 + (i * 16 + ty) * 128 + (j * 16 + tx);
    out[gi] = backbone[gi] + X[tok * C_DIM + c];
}

// ---------------- defe mask: non-overlapping 16x16 maxpool > 0 ----------------
__global__ void mask_kernel(const float* __restrict__ defe, float* __restrict__ out) {
    int idx = threadIdx.x;           // 0..127
    if (idx >= 128) return;
    int b = idx >> 6;
    int ii = (idx >> 3) & 7;
    int jj = idx & 7;
    float mx = -1e30f;
    for (int y = 0; y < 16; ++y)
        for (int x = 0; x < 16; ++x)
            mx = fmaxf(mx, defe[b * 16384 + (ii * 16 + y) * 128 + (jj * 16 + x)]);
    out[8388608 + idx] = (mx > 0.0f) ? 1.0f : 0.0f;
}

extern "C" void kernel_launch(void* const* d_in, const int* in_sizes, int n_in,
                              void* d_out, int out_size, void* d_ws, size_t ws_size,
                              hipStream_t stream) {
    const float* backbone = (const float*)d_in[0];
    const float* defe     = (const float*)d_in[1];
    const float* glob     = (const float*)d_in[2];
    const float* Wqkv     = (const float*)d_in[3];
    const float* bqkv     = (const float*)d_in[4];
    const float* Wo       = (const float*)d_in[5];
    const float* bo       = (const float*)d_in[6];
    const float* W1       = (const float*)d_in[7];
    const float* b1       = (const float*)d_in[8];
    const float* W2       = (const float*)d_in[9];
    const float* b2       = (const float*)d_in[10];
    const float* g1       = (const float*)d_in[11];
    const float* be1      = (const float*)d_in[12];
    const float* g2       = (const float*)d_in[13];
    const float* be2      = (const float*)d_in[14];
    const float* relW1    = (const float*)d_in[15];
    const float* relb1    = (const float*)d_in[16];
    const float* relW2    = (const float*)d_in[17];
    const float* relb2    = (const float*)d_in[18];

    // workspace layout (floats)
    float* ws  = (float*)d_ws;
    float* rel = ws;                       //      65,536
    float* pe  = rel + 65536;              //   4,194,304
    float* X   = pe + 4194304;             //   8,388,608
    float* QK  = X + 8388608;              //  16,777,216  (also reused as FFN hidden H)
    float* Vb  = QK + 16777216;            //   8,388,608  (V proj, then proj-out / FFN-out Y)
    size_t needed = (size_t)(65536 + 4194304 + 8388608 + 16777216 + 8388608) * 4;
    if (ws_size < needed) return;  // insufficient scratch; bail (test will flag)

    rel_pe_kernel<<<HWTOK, 256, 0, stream>>>(relW1, relb1, relW2, relb2, rel);
    build_pe_kernel<<<PETOK, 256, 0, stream>>>(glob, rel, pe);
    window_kernel<<<NTOK, 256, 0, stream>>>(backbone, X);

    for (int pass = 0; pass < 2; ++pass) {
        // QK projection: [32768 x 512] = (X + pe) * Wqk^T + bqk
        gemm_kernel<<<dim3(512 / 64, NTOK / 64), 256, 0, stream>>>(
            X, C_DIM, pe, Wqkv, bqkv, QK, 512, C_DIM, 0);
        // V projection: [32768 x 256] = X * Wv^T + bv
        gemm_kernel<<<dim3(256 / 64, NTOK / 64), 256, 0, stream>>>(
            X, C_DIM, nullptr, Wqkv + 512 * 256, bqkv + 512, Vb, C_DIM, C_DIM, 0);
        // attention (O in-place over Q half of QK)
        if (pass == 0) {
            // seq = t (256), batch = (b, v) : 128 * 8 heads
            attn_kernel<<<128 * NHEAD, 256, 2 * 256 * 33 * sizeof(float), stream>>>(
                QK, Vb, QK, 256, 64, 256, 1);
        } else {
            // seq = v (64), batch = (b, t) : 512 * 8 heads
            attn_kernel<<<512 * NHEAD, 64, 2 * 64 * 33 * sizeof(float), stream>>>(
                QK, Vb, QK, 64, 256, 1, 256);
        }
        // out projection: Y(=Vb) = O * Wo^T + bo
        gemm_kernel<<<dim3(256 / 64, NTOK / 64), 256, 0, stream>>>(
            QK, 512, nullptr, Wo, bo, Vb, C_DIM, C_DIM, 0);
        // src = LN(X + Y) -> X
        ln_kernel<<<NTOK / 4, 256, 0, stream>>>(X, Vb, g1, be1, 0);
        // FFN in 2 token-chunks of 16384 (H reuses QK buffer)
        for (int ch = 0; ch < 2; ++ch) {
            int t0 = ch * 16384;
            gemm_kernel<<<dim3(DFF_DIM / 64, 16384 / 64), 256, 0, stream>>>(
                X + t0 * C_DIM, C_DIM, nullptr, W1, b1, QK, DFF_DIM, C_DIM, 1);
            gemm_kernel<<<dim3(256 / 64, 16384 / 64), 256, 0, stream>>>(
                QK, DFF_DIM, nullptr, W2, b2, Vb + t0 * C_DIM, C_DIM, DFF_DIM, 0);
            ln_kernel<<<16384 / 4, 256, 0, stream>>>(X, Vb, g2, be2, t0);
        }
    }

    scatter_kernel<<<NTOK, 256, 0, stream>>>(backbone, X, (float*)d_out);
    mask_kernel<<<1, 128, 0, stream>>>(defe, (float*)d_out);
}

// Round 2
// 1200.512 us; speedup vs baseline: 1.7568x; 1.7568x over previous
//
#include <hip/hip_runtime.h>
#include <hip/hip_bf16.h>

#define C_DIM 256
#define NHEAD 8
#define DH 32
#define NTOK 32768   // B * Nv * hw
#define PETOK 16384  // Nv * hw
#define DFF_DIM 1024
#define LN_EPS 1e-5f

typedef unsigned int u32;
typedef unsigned short ushortT;
using frag_ab = __attribute__((ext_vector_type(8))) short;
using f32x4   = __attribute__((ext_vector_type(4))) float;

__device__ __forceinline__ float bflo(u32 u) { union { u32 i; float f; } c; c.i = u << 16; return c.f; }
__device__ __forceinline__ float bfhi(u32 u) { union { u32 i; float f; } c; c.i = u & 0xffff0000u; return c.f; }
__device__ __forceinline__ ushortT f2b(float f) {
    __hip_bfloat16 b = __float2bfloat16(f);
    return *reinterpret_cast<ushortT*>(&b);
}
__device__ __forceinline__ u32 packbf(float lo, float hi) {
    return (u32)f2b(lo) | ((u32)f2b(hi) << 16);
}

// ---------------- fp32 -> bf16 converter (weights) ----------------
__global__ void cvt_kernel(const float* __restrict__ src, ushortT* __restrict__ dst, int n) {
    int i = blockIdx.x * 256 + threadIdx.x;
    if (i < n) dst[i] = f2b(src[i]);
}

// ---------------- pe (bf16) = glob windowed + rel-MLP ----------------
__global__ void build_pe_kernel(const float* __restrict__ glob,
                                const float* __restrict__ relW1, const float* __restrict__ relb1,
                                const float* __restrict__ relW2, const float* __restrict__ relb2,
                                ushortT* __restrict__ peb) {
    __shared__ float hid[64];
    int vt = blockIdx.x;                 // v*256 + t
    int v = vt >> 8, t = vt & 255;
    int i = v >> 3, j = v & 7;
    int ty = t >> 4, tx = t & 15;
    float cx = tx * (1.0f / 15.0f);
    float cy = ty * (1.0f / 15.0f);
    int c = threadIdx.x;
    if (c < 64) {
        float h = relW1[c * 2 + 0] * cx + relW1[c * 2 + 1] * cy + relb1[c];
        hid[c] = fmaxf(h, 0.0f);
    }
    __syncthreads();
    float acc = relb2[c];
    #pragma unroll
    for (int jj = 0; jj < 64; ++jj) acc = fmaf(hid[jj], relW2[c * 64 + jj], acc);
    int gidx = c * 16384 + (i * 16 + ty) * 128 + (j * 16 + tx);
    peb[vt * C_DIM + c] = f2b(glob[gidx] + acc);
}

// ---------------- window partition -> Xf (fp32) + Xb (bf16) ----------------
__global__ void window_kernel(const float* __restrict__ backbone,
                              float* __restrict__ Xf, ushortT* __restrict__ Xb) {
    int tok = blockIdx.x;
    int b = tok >> 14;
    int vt = tok & 16383;
    int v = vt >> 8, t = vt & 255;
    int i = v >> 3, j = v & 7, ty = t >> 4, tx = t & 15;
    int c = threadIdx.x;
    float val = backbone[b * 4194304 + c * 16384 + (i * 16 + ty) * 128 + (j * 16 + tx)];
    Xf[tok * C_DIM + c] = val;
    Xb[tok * C_DIM + c] = f2b(val);
}

// ---------------- bf16 MFMA GEMM: C = A * W^T + bias ----------------
// A: [M x lda] bf16.  W: [N x K] bf16.  C: [M x ldc] bf16.
// FUSE_PE: A-tile = bf16(A + peb[tok & 16383]) staged in fp32 add.
#define BM 128
#define BN 128
#define BK 32
#define LDT 40   // padded LDS stride (bf16 elems): 80B row stride, 16B-aligned frags, 2-way banks

template<bool FUSE_PE, bool RELU>
__global__ __launch_bounds__(256) void gemm_bf16(
        const ushortT* __restrict__ A, int lda,
        const ushortT* __restrict__ peb,
        const ushortT* __restrict__ W,
        const float* __restrict__ bias,
        ushortT* __restrict__ Cout, int ldc, int K) {
    __shared__ ushortT As[BM][LDT];
    __shared__ ushortT Bs[BN][LDT];
    const int m0 = blockIdx.y * BM;
    const int n0 = blockIdx.x * BN;
    const int tid = threadIdx.x;
    const int lane = tid & 63;
    const int wave = tid >> 6;
    const int wm = (wave >> 1) * 64;
    const int wn = (wave & 1) * 64;
    const int fr = lane & 15;          // fragment row/col
    const int fg = lane >> 4;          // k-group (0..3)
    const int sRow = tid >> 2;         // staging row 0..63 (+64)
    const int sCol = (tid & 3) * 8;    // staging col (elements)

    f32x4 acc[4][4];
    #pragma unroll
    for (int i = 0; i < 4; ++i)
        #pragma unroll
        for (int j = 0; j < 4; ++j)
            acc[i][j] = (f32x4){0.f, 0.f, 0.f, 0.f};

    for (int k0 = 0; k0 < K; k0 += BK) {
        #pragma unroll
        for (int h = 0; h < 2; ++h) {
            const int row = sRow + h * 64;
            uint4 av = *(const uint4*)&A[(size_t)(m0 + row) * lda + k0 + sCol];
            if (FUSE_PE) {
                const uint4 pv = *(const uint4*)&peb[(size_t)((m0 + row) & 16383) * C_DIM + k0 + sCol];
                u32* a = (u32*)&av;
                const u32* p = (const u32*)&pv;
                #pragma unroll
                for (int e = 0; e < 4; ++e)
                    a[e] = packbf(bflo(a[e]) + bflo(p[e]), bfhi(a[e]) + bfhi(p[e]));
            }
            *(uint4*)&As[row][sCol] = av;
            const uint4 bv = *(const uint4*)&W[(size_t)(n0 + row) * K + k0 + sCol];
            *(uint4*)&Bs[row][sCol] = bv;
        }
        __syncthreads();
        frag_ab af[4], bf[4];
        #pragma unroll
        for (int i = 0; i < 4; ++i) af[i] = *(const frag_ab*)&As[wm + i * 16 + fr][fg * 8];
        #pragma unroll
        for (int j = 0; j < 4; ++j) bf[j] = *(const frag_ab*)&Bs[wn + j * 16 + fr][fg * 8];
        #pragma unroll
        for (int i = 0; i < 4; ++i)
            #pragma unroll
            for (int j = 0; j < 4; ++j)
                acc[i][j] = __builtin_amdgcn_mfma_f32_16x16x32_bf16(af[i], bf[j], acc[i][j], 0, 0, 0);
        __syncthreads();
    }
    // epilogue: D row = (lane>>4)*4 + reg, col = lane&15 (per fragment)
    #pragma unroll
    for (int j = 0; j < 4; ++j) {
        const float bv = bias[n0 + wn + j * 16 + fr];
        #pragma unroll
        for (int i = 0; i < 4; ++i) {
            #pragma unroll
            for (int r = 0; r < 4; ++r) {
                float v = acc[i][j][r] + bv;
                if (RELU) v = fmaxf(v, 0.0f);
                const int m = m0 + wm + i * 16 + fg * 4 + r;
                const int n = n0 + wn + j * 16 + fr;
                Cout[(size_t)m * ldc + n] = f2b(v);
            }
        }
    }
}

// ---------------- attention (online softmax, bf16 IO, fp32 math) ----------------
// QKb: [NTOK x 512] bf16 (Q | K).  Vb: [NTOK x 256] bf16.  O: [NTOK x 256] bf16.
// tok(bat,row) = (bat/perB)*16384 + (bat%perB)*innerStride + row*seqStride
__global__ __launch_bounds__(256) void attn_kernel(
        const ushortT* __restrict__ QKb, const ushortT* __restrict__ Vb,
        ushortT* __restrict__ O, int S, int perB, int innerStride, int seqStride) {
    extern __shared__ float sm[];
    float* Ks = sm;                  // [S][33]
    float* Vs = sm + S * 33;
    int bat = blockIdx.x / NHEAD;
    int head = blockIdx.x % NHEAD;
    int b = bat / perB, r = bat % perB;
    int base = b * PETOK + r * innerStride;
    int row = threadIdx.x;
    int tok = base + row * seqStride;

    const ushortT* kp = &QKb[(size_t)tok * 512 + 256 + head * DH];
    const ushortT* vp = &Vb[(size_t)tok * C_DIM + head * DH];
    const ushortT* qp = &QKb[(size_t)tok * 512 + head * DH];
    float q[DH];
    #pragma unroll
    for (int d0 = 0; d0 < DH; d0 += 8) {
        const uint4 ku = *(const uint4*)&kp[d0];
        const uint4 vu = *(const uint4*)&vp[d0];
        const uint4 qu = *(const uint4*)&qp[d0];
        const u32 kw[4] = {ku.x, ku.y, ku.z, ku.w};
        const u32 vw[4] = {vu.x, vu.y, vu.z, vu.w};
        const u32 qw[4] = {qu.x, qu.y, qu.z, qu.w};
        #pragma unroll
        for (int e = 0; e < 4; ++e) {
            Ks[row * 33 + d0 + 2 * e + 0] = bflo(kw[e]);
            Ks[row * 33 + d0 + 2 * e + 1] = bfhi(kw[e]);
            Vs[row * 33 + d0 + 2 * e + 0] = bflo(vw[e]);
            Vs[row * 33 + d0 + 2 * e + 1] = bfhi(vw[e]);
            q[d0 + 2 * e + 0] = bflo(qw[e]);
            q[d0 + 2 * e + 1] = bfhi(qw[e]);
        }
    }
    __syncthreads();

    const float scale = 0.17677669529663687f;   // 1/sqrt(32)
    float m = -1e30f, l = 0.0f;
    float acc[DH];
    #pragma unroll
    for (int d = 0; d < DH; ++d) acc[d] = 0.0f;
    for (int k = 0; k < S; ++k) {
        const float* kr = &Ks[k * 33];
        float s0 = 0.f, s1 = 0.f, s2 = 0.f, s3 = 0.f;    // 4-way ILP on the dot chain
        #pragma unroll
        for (int d = 0; d < DH; d += 4) {
            s0 = fmaf(q[d + 0], kr[d + 0], s0);
            s1 = fmaf(q[d + 1], kr[d + 1], s1);
            s2 = fmaf(q[d + 2], kr[d + 2], s2);
            s3 = fmaf(q[d + 3], kr[d + 3], s3);
        }
        float s = ((s0 + s1) + (s2 + s3)) * scale;
        float nm = fmaxf(m, s);
        float corr = __expf(m - nm);
        float p = __expf(s - nm);
        l = l * corr + p;
        const float* vr = &Vs[k * 33];
        #pragma unroll
        for (int d = 0; d < DH; ++d) acc[d] = fmaf(acc[d], corr, p * vr[d]);
        m = nm;
    }
    float inv = 1.0f / l;
    u32* op = (u32*)&O[(size_t)tok * C_DIM + head * DH];
    #pragma unroll
    for (int d = 0; d < DH; d += 2) op[d >> 1] = packbf(acc[d] * inv, acc[d + 1] * inv);
}

// ---------------- residual + LayerNorm: Xf = LN(Xf + Yb)*g + b ; Xb = bf16(Xf) ----------------
__global__ __launch_bounds__(256) void ln_kernel(float* __restrict__ X, const ushortT* __restrict__ Y,
                                                 const float* __restrict__ g, const float* __restrict__ be,
                                                 ushortT* __restrict__ Xb) {
    int tok = blockIdx.x * 4 + (threadIdx.x >> 6);
    int lane = threadIdx.x & 63;
    float4 x = *(float4*)&X[(size_t)tok * C_DIM + lane * 4];
    const uint2 yu = *(const uint2*)&Y[(size_t)tok * C_DIM + lane * 4];
    float v0 = x.x + bflo(yu.x), v1 = x.y + bfhi(yu.x);
    float v2 = x.z + bflo(yu.y), v3 = x.w + bfhi(yu.y);
    float s = v0 + v1 + v2 + v3;
    float ss = v0 * v0 + v1 * v1 + v2 * v2 + v3 * v3;
    #pragma unroll
    for (int off = 32; off; off >>= 1) {
        s += __shfl_xor(s, off, 64);
        ss += __shfl_xor(ss, off, 64);
    }
    float mean = s * (1.0f / 256.0f);
    float var = ss * (1.0f / 256.0f) - mean * mean;
    float inv = rsqrtf(var + LN_EPS);
    const float4 gv = *(const float4*)&g[lane * 4];
    const float4 bv = *(const float4*)&be[lane * 4];
    float o0 = (v0 - mean) * inv * gv.x + bv.x;
    float o1 = (v1 - mean) * inv * gv.y + bv.y;
    float o2 = (v2 - mean) * inv * gv.z + bv.z;
    float o3 = (v3 - mean) * inv * gv.w + bv.w;
    float4 of = {o0, o1, o2, o3};
    *(float4*)&X[(size_t)tok * C_DIM + lane * 4] = of;
    uint2 ob = {packbf(o0, o1), packbf(o2, o3)};
    *(uint2*)&Xb[(size_t)tok * C_DIM + lane * 4] = ob;
}

// ---------------- scatter back + residual ----------------
__global__ void scatter_kernel(const float* __restrict__ backbone, const float* __restrict__ X,
                               float* __restrict__ out) {
    int tok = blockIdx.x;
    int b = tok >> 14;
    int vt = tok & 16383;
    int v = vt >> 8, t = vt & 255;
    int i = v >> 3, j = v & 7, ty = t >> 4, tx = t & 15;
    int c = threadIdx.x;
    int gi = b * 4194304 + c * 16384 + (i * 16 + ty) * 128 + (j * 16 + tx);
    out[gi] = backbone[gi] + X[(size_t)tok * C_DIM + c];
}

// ---------------- defe mask ----------------
__global__ void mask_kernel(const float* __restrict__ defe, float* __restrict__ out) {
    int idx = threadIdx.x;
    if (idx >= 128) return;
    int b = idx >> 6;
    int ii = (idx >> 3) & 7;
    int jj = idx & 7;
    float mx = -1e30f;
    for (int y = 0; y < 16; ++y)
        for (int x = 0; x < 16; ++x)
            mx = fmaxf(mx, defe[b * 16384 + (ii * 16 + y) * 128 + (jj * 16 + x)]);
    out[8388608 + idx] = (mx > 0.0f) ? 1.0f : 0.0f;
}

extern "C" void kernel_launch(void* const* d_in, const int* in_sizes, int n_in,
                              void* d_out, int out_size, void* d_ws, size_t ws_size,
                              hipStream_t stream) {
    const float* backbone = (const float*)d_in[0];
    const float* defe     = (const float*)d_in[1];
    const float* glob     = (const float*)d_in[2];
    const float* Wqkv     = (const float*)d_in[3];
    const float* bqkv     = (const float*)d_in[4];
    const float* Wo       = (const float*)d_in[5];
    const float* bo       = (const float*)d_in[6];
    const float* W1       = (const float*)d_in[7];
    const float* b1       = (const float*)d_in[8];
    const float* W2       = (const float*)d_in[9];
    const float* b2       = (const float*)d_in[10];
    const float* g1       = (const float*)d_in[11];
    const float* be1      = (const float*)d_in[12];
    const float* g2       = (const float*)d_in[13];
    const float* be2      = (const float*)d_in[14];
    const float* relW1    = (const float*)d_in[15];
    const float* relb1    = (const float*)d_in[16];
    const float* relW2    = (const float*)d_in[17];
    const float* relb2    = (const float*)d_in[18];

    // workspace layout (ushort units for bf16, then fp32 Xf)
    ushortT* peb    = (ushortT*)d_ws;                       //  4,194,304
    ushortT* Wqkv_b = peb + 4194304;                        //    196,608
    ushortT* Wo_b   = Wqkv_b + 196608;                      //     65,536
    ushortT* W1_b   = Wo_b + 65536;                         //    262,144
    ushortT* W2_b   = W1_b + 262144;                        //    262,144
    ushortT* Xb     = W2_b + 262144;                        //  8,388,608
    ushortT* QKb    = Xb + 8388608;                         // 16,777,216  (R1 base; aliased as H)
    ushortT* Vb     = QKb + 16777216;                       //  8,388,608
    ushortT* Ob     = Vb + 8388608;                         //  8,388,608
    ushortT* Hb     = QKb;                                  // 33,554,432 (= QKb+Vb+Ob exactly)
    ushortT* Yb     = Ob + 8388608;                         //  8,388,608
    float*   Xf     = (float*)(Yb + 8388608);               //  8,388,608 floats
    size_t needed = (size_t)((char*)(Xf + 8388608) - (char*)d_ws);
    if (ws_size < needed) return;

    // weight conversions (once per launch; tiny)
    cvt_kernel<<<(196608 + 255) / 256, 256, 0, stream>>>(Wqkv, Wqkv_b, 196608);
    cvt_kernel<<<(65536 + 255) / 256, 256, 0, stream>>>(Wo, Wo_b, 65536);
    cvt_kernel<<<(262144 + 255) / 256, 256, 0, stream>>>(W1, W1_b, 262144);
    cvt_kernel<<<(262144 + 255) / 256, 256, 0, stream>>>(W2, W2_b, 262144);

    build_pe_kernel<<<PETOK, 256, 0, stream>>>(glob, relW1, relb1, relW2, relb2, peb);
    window_kernel<<<NTOK, 256, 0, stream>>>(backbone, Xf, Xb);

    for (int pass = 0; pass < 2; ++pass) {
        // QK projection (pe fused): [32768 x 512]
        gemm_bf16<true, false><<<dim3(512 / BN, NTOK / BM), 256, 0, stream>>>(
            Xb, C_DIM, peb, Wqkv_b, bqkv, QKb, 512, C_DIM);
        // V projection: [32768 x 256]
        gemm_bf16<false, false><<<dim3(256 / BN, NTOK / BM), 256, 0, stream>>>(
            Xb, C_DIM, nullptr, Wqkv_b + 512 * 256, bqkv + 512, Vb, C_DIM, C_DIM);
        // attention
        if (pass == 0) {
            attn_kernel<<<128 * NHEAD, 256, 2 * 256 * 33 * sizeof(float), stream>>>(
                QKb, Vb, Ob, 256, 64, 256, 1);
        } else {
            attn_kernel<<<512 * NHEAD, 64, 2 * 64 * 33 * sizeof(float), stream>>>(
                QKb, Vb, Ob, 64, 256, 1, 256);
        }
        // out projection -> Yb
        gemm_bf16<false, false><<<dim3(256 / BN, NTOK / BM), 256, 0, stream>>>(
            Ob, C_DIM, nullptr, Wo_b, bo, Yb, C_DIM, C_DIM);
        // LN1: Xf = LN(Xf + Yb), Xb = bf16(Xf)
        ln_kernel<<<NTOK / 4, 256, 0, stream>>>(Xf, Yb, g1, be1, Xb);
        // FFN (H aliases the dead QK|V|O region)
        gemm_bf16<false, true><<<dim3(DFF_DIM / BN, NTOK / BM), 256, 0, stream>>>(
            Xb, C_DIM, nullptr, W1_b, b1, Hb, DFF_DIM, C_DIM);
        gemm_bf16<false, false><<<dim3(256 / BN, NTOK / BM), 256, 0, stream>>>(
            Hb, DFF_DIM, nullptr, W2_b, b2, Yb, C_DIM, DFF_DIM);
        // LN2
        ln_kernel<<<NTOK / 4, 256, 0, stream>>>(Xf, Yb, g2, be2, Xb);
    }

    scatter_kernel<<<NTOK, 256, 0, stream>>>(backbone, Xf, (float*)d_out);
    mask_kernel<<<1, 128, 0, stream>>>(defe, (float*)d_out);
}

// Round 3
// 683.615 us; speedup vs baseline: 3.0851x; 1.7561x over previous
//
#include <hip/hip_runtime.h>
#include <hip/hip_bf16.h>

#define C_DIM 256
#define NHEAD 8
#define DH 32
#define NTOK 32768   // B * Nv * hw
#define PETOK 16384  // Nv * hw
#define DFF_DIM 1024
#define LN_EPS 1e-5f

typedef unsigned int u32;
typedef unsigned short ushortT;
using frag_ab = __attribute__((ext_vector_type(8))) short;
using f32x4   = __attribute__((ext_vector_type(4))) float;

__device__ __forceinline__ float bflo(u32 u) { union { u32 i; float f; } c; c.i = u << 16; return c.f; }
__device__ __forceinline__ float bfhi(u32 u) { union { u32 i; float f; } c; c.i = u & 0xffff0000u; return c.f; }
__device__ __forceinline__ ushortT f2b(float f) {
    __hip_bfloat16 b = __float2bfloat16(f);
    return *reinterpret_cast<ushortT*>(&b);
}
__device__ __forceinline__ u32 packbf(float lo, float hi) {
    return (u32)f2b(lo) | ((u32)f2b(hi) << 16);
}

// ---------------- fp32 -> bf16 converter (weights) ----------------
__global__ void cvt_kernel(const float* __restrict__ src, ushortT* __restrict__ dst, int n) {
    int i = blockIdx.x * 256 + threadIdx.x;
    if (i < n) dst[i] = f2b(src[i]);
}

// ---------------- pe (bf16) = glob windowed + rel-MLP ----------------
__global__ void build_pe_kernel(const float* __restrict__ glob,
                                const float* __restrict__ relW1, const float* __restrict__ relb1,
                                const float* __restrict__ relW2, const float* __restrict__ relb2,
                                ushortT* __restrict__ peb) {
    __shared__ float hid[64];
    int vt = blockIdx.x;                 // v*256 + t
    int v = vt >> 8, t = vt & 255;
    int i = v >> 3, j = v & 7;
    int ty = t >> 4, tx = t & 15;
    float cx = tx * (1.0f / 15.0f);
    float cy = ty * (1.0f / 15.0f);
    int c = threadIdx.x;
    if (c < 64) {
        float h = relW1[c * 2 + 0] * cx + relW1[c * 2 + 1] * cy + relb1[c];
        hid[c] = fmaxf(h, 0.0f);
    }
    __syncthreads();
    float acc = relb2[c];
    #pragma unroll
    for (int jj = 0; jj < 64; ++jj) acc = fmaf(hid[jj], relW2[c * 64 + jj], acc);
    int gidx = c * 16384 + (i * 16 + ty) * 128 + (j * 16 + tx);
    peb[vt * C_DIM + c] = f2b(glob[gidx] + acc);
}

// ---------------- window partition -> Xf (fp32) + Xb (bf16) ----------------
__global__ void window_kernel(const float* __restrict__ backbone,
                              float* __restrict__ Xf, ushortT* __restrict__ Xb) {
    int tok = blockIdx.x;
    int b = tok >> 14;
    int vt = tok & 16383;
    int v = vt >> 8, t = vt & 255;
    int i = v >> 3, j = v & 7, ty = t >> 4, tx = t & 15;
    int c = threadIdx.x;
    float val = backbone[b * 4194304 + c * 16384 + (i * 16 + ty) * 128 + (j * 16 + tx)];
    Xf[tok * C_DIM + c] = val;
    Xb[tok * C_DIM + c] = f2b(val);
}

// ---------------- bf16 MFMA GEMM: C = A * W^T + bias ----------------
#define BM 128
#define BN 128
#define BK 32
#define LDT 40   // padded LDS stride (bf16 elems)

template<bool FUSE_PE, bool RELU>
__global__ __launch_bounds__(256) void gemm_bf16(
        const ushortT* __restrict__ A, int lda,
        const ushortT* __restrict__ peb,
        const ushortT* __restrict__ W,
        const float* __restrict__ bias,
        ushortT* __restrict__ Cout, int ldc, int K) {
    __shared__ ushortT As[BM][LDT];
    __shared__ ushortT Bs[BN][LDT];
    const int m0 = blockIdx.y * BM;
    const int n0 = blockIdx.x * BN;
    const int tid = threadIdx.x;
    const int lane = tid & 63;
    const int wave = tid >> 6;
    const int wm = (wave >> 1) * 64;
    const int wn = (wave & 1) * 64;
    const int fr = lane & 15;
    const int fg = lane >> 4;
    const int sRow = tid >> 2;
    const int sCol = (tid & 3) * 8;

    f32x4 acc[4][4];
    #pragma unroll
    for (int i = 0; i < 4; ++i)
        #pragma unroll
        for (int j = 0; j < 4; ++j)
            acc[i][j] = (f32x4){0.f, 0.f, 0.f, 0.f};

    for (int k0 = 0; k0 < K; k0 += BK) {
        #pragma unroll
        for (int h = 0; h < 2; ++h) {
            const int row = sRow + h * 64;
            uint4 av = *(const uint4*)&A[(size_t)(m0 + row) * lda + k0 + sCol];
            if (FUSE_PE) {
                const uint4 pv = *(const uint4*)&peb[(size_t)((m0 + row) & 16383) * C_DIM + k0 + sCol];
                u32* a = (u32*)&av;
                const u32* p = (const u32*)&pv;
                #pragma unroll
                for (int e = 0; e < 4; ++e)
                    a[e] = packbf(bflo(a[e]) + bflo(p[e]), bfhi(a[e]) + bfhi(p[e]));
            }
            *(uint4*)&As[row][sCol] = av;
            const uint4 bv = *(const uint4*)&W[(size_t)(n0 + row) * K + k0 + sCol];
            *(uint4*)&Bs[row][sCol] = bv;
        }
        __syncthreads();
        frag_ab af[4], bf[4];
        #pragma unroll
        for (int i = 0; i < 4; ++i) af[i] = *(const frag_ab*)&As[wm + i * 16 + fr][fg * 8];
        #pragma unroll
        for (int j = 0; j < 4; ++j) bf[j] = *(const frag_ab*)&Bs[wn + j * 16 + fr][fg * 8];
        #pragma unroll
        for (int i = 0; i < 4; ++i)
            #pragma unroll
            for (int j = 0; j < 4; ++j)
                acc[i][j] = __builtin_amdgcn_mfma_f32_16x16x32_bf16(af[i], bf[j], acc[i][j], 0, 0, 0);
        __syncthreads();
    }
    #pragma unroll
    for (int j = 0; j < 4; ++j) {
        const float bv = bias[n0 + wn + j * 16 + fr];
        #pragma unroll
        for (int i = 0; i < 4; ++i) {
            #pragma unroll
            for (int r = 0; r < 4; ++r) {
                float v = acc[i][j][r] + bv;
                if (RELU) v = fmaxf(v, 0.0f);
                const int m = m0 + wm + i * 16 + fg * 4 + r;
                const int n = n0 + wn + j * 16 + fr;
                Cout[(size_t)m * ldc + n] = f2b(v);
            }
        }
    }
}

// ---------------- MFMA flash attention ----------------
// Scores via swapped mfma(K_frag, Q_frag): C col = lane&15 = query, row = key.
// Softmax fully in-register (per-lane S/4 values + shfl_xor 16/32).
// P -> per-wave LDS [16q][S+pad] bf16 (b64 writes, b128 B-frag reads).
// PV via mfma(V_t_frag, P_frag) with V staged transposed: V_t[d][key].
template<int S, int LDK, int LDV, int LDP>
__device__ __forceinline__ void attn_wave_work(
        const ushortT* __restrict__ QKb, ushortT* __restrict__ Ob,
        const ushortT* __restrict__ K_lds, const ushortT* __restrict__ V_t,
        ushortT* __restrict__ P_lds,
        int base, int seqStride, int head, int q0base) {
    constexpr int NKT = S / 16;
    constexpr int NKC = S / 32;
    const int lane = threadIdx.x & 63;
    const int fr = lane & 15;
    const int fg = lane >> 4;
    const float scale = 0.17677669529663687f;   // 1/sqrt(32)
    #pragma unroll
    for (int s = 0; s < 4; ++s) {
        const int qq = q0base + s * 16 + fr;
        const size_t qtok = (size_t)(base + qq * seqStride);
        const frag_ab qf = *(const frag_ab*)&QKb[qtok * 512 + head * DH + fg * 8];
        f32x4 sc[NKT];
        #pragma unroll
        for (int kt = 0; kt < NKT; ++kt) {
            const frag_ab kf = *(const frag_ab*)&K_lds[(kt * 16 + fr) * LDK + fg * 8];
            sc[kt] = __builtin_amdgcn_mfma_f32_16x16x32_bf16(kf, qf, (f32x4){0.f, 0.f, 0.f, 0.f}, 0, 0, 0);
        }
        float mx = -1e30f;
        #pragma unroll
        for (int kt = 0; kt < NKT; ++kt)
            mx = fmaxf(mx, fmaxf(fmaxf(sc[kt][0], sc[kt][1]), fmaxf(sc[kt][2], sc[kt][3])));
        mx = fmaxf(mx, __shfl_xor(mx, 16, 64));
        mx = fmaxf(mx, __shfl_xor(mx, 32, 64));
        float lsum = 0.f;
        #pragma unroll
        for (int kt = 0; kt < NKT; ++kt) {
            const float p0 = __expf((sc[kt][0] - mx) * scale);
            const float p1 = __expf((sc[kt][1] - mx) * scale);
            const float p2 = __expf((sc[kt][2] - mx) * scale);
            const float p3 = __expf((sc[kt][3] - mx) * scale);
            lsum += (p0 + p1) + (p2 + p3);
            uint2 pk;
            pk.x = packbf(p0, p1);
            pk.y = packbf(p2, p3);
            *(uint2*)&P_lds[fr * LDP + kt * 16 + fg * 4] = pk;   // keys 16kt+4fg..+3 of query fr
        }
        lsum += __shfl_xor(lsum, 16, 64);
        lsum += __shfl_xor(lsum, 32, 64);
        f32x4 o0 = {0.f, 0.f, 0.f, 0.f}, o1 = {0.f, 0.f, 0.f, 0.f};
        #pragma unroll
        for (int kc = 0; kc < NKC; ++kc) {
            const frag_ab pf = *(const frag_ab*)&P_lds[fr * LDP + kc * 32 + fg * 8];
            const frag_ab v0 = *(const frag_ab*)&V_t[fr * LDV + kc * 32 + fg * 8];
            const frag_ab v1 = *(const frag_ab*)&V_t[(16 + fr) * LDV + kc * 32 + fg * 8];
            o0 = __builtin_amdgcn_mfma_f32_16x16x32_bf16(v0, pf, o0, 0, 0, 0);
            o1 = __builtin_amdgcn_mfma_f32_16x16x32_bf16(v1, pf, o1, 0, 0, 0);
        }
        const float inv = 1.0f / lsum;
        ushortT* ob = &Ob[qtok * C_DIM + head * DH];
        uint2 w0, w1;
        w0.x = packbf(o0[0] * inv, o0[1] * inv);
        w0.y = packbf(o0[2] * inv, o0[3] * inv);
        w1.x = packbf(o1[0] * inv, o1[1] * inv);
        w1.y = packbf(o1[2] * inv, o1[3] * inv);
        *(uint2*)&ob[fg * 4] = w0;          // d = fg*4 + r
        *(uint2*)&ob[16 + fg * 4] = w1;     // d = 16 + fg*4 + r
    }
}

// pass 0: block = (b, v, head); 4 waves share K/V_t, each owns 64 queries
__global__ __launch_bounds__(256) void attn_p0(const ushortT* __restrict__ QKb,
                                               const ushortT* __restrict__ Vb,
                                               ushortT* __restrict__ Ob) {
    __shared__ ushortT K_lds[256 * 40];      // 20.0 KB
    __shared__ ushortT V_t[32 * 272];        // 17.0 KB
    __shared__ ushortT P_lds[4][16 * 264];   // 33.0 KB
    const int grp = blockIdx.x;              // (b*64+v)*8 + h
    const int h = grp & 7;
    const int bv = grp >> 3;
    const int base = (bv >> 6) * PETOK + (bv & 63) * 256;
    const int tid = threadIdx.x;
    #pragma unroll
    for (int it = 0; it < 4; ++it) {
        const int idx = it * 256 + tid;
        const int row = idx >> 2, ch = idx & 3;
        const size_t tok = (size_t)(base + row);
        const uint4 kv = *(const uint4*)&QKb[tok * 512 + 256 + h * DH + ch * 8];
        *(uint4*)&K_lds[row * 40 + ch * 8] = kv;
        const uint4 vv = *(const uint4*)&Vb[tok * C_DIM + h * DH + ch * 8];
        const ushortT* vp = (const ushortT*)&vv;
        #pragma unroll
        for (int e = 0; e < 8; ++e) V_t[(ch * 8 + e) * 272 + row] = vp[e];
    }
    __syncthreads();
    const int wave = tid >> 6;
    attn_wave_work<256, 40, 272, 264>(QKb, Ob, K_lds, V_t, P_lds[wave], base, 1, h, wave * 64);
}

// pass 1: 4 independent waves per block, wave = one (b, t, head), S=64, no barriers
__global__ __launch_bounds__(256) void attn_p1(const ushortT* __restrict__ QKb,
                                               const ushortT* __restrict__ Vb,
                                               ushortT* __restrict__ Ob) {
    __shared__ ushortT K_lds[4][64 * 40];    // 20.0 KB
    __shared__ ushortT V_t[4][32 * 72];      // 18.0 KB
    __shared__ ushortT P_lds[4][16 * 72];    //  9.0 KB
    const int wave = threadIdx.x >> 6;
    const int lane = threadIdx.x & 63;
    const int unit = blockIdx.x * 4 + wave;  // 0..4095 = (b*256 + t)*8 + h
    const int h = unit & 7;
    const int g = unit >> 3;                 // 0..511
    const int base = (g >> 8) * PETOK + (g & 255);
    #pragma unroll
    for (int it = 0; it < 4; ++it) {
        const int idx = it * 64 + lane;
        const int row = idx >> 2, ch = idx & 3;
        const size_t tok = (size_t)(base + row * 256);
        const uint4 kv = *(const uint4*)&QKb[tok * 512 + 256 + h * DH + ch * 8];
        *(uint4*)&K_lds[wave][row * 40 + ch * 8] = kv;
        const uint4 vv = *(const uint4*)&Vb[tok * C_DIM + h * DH + ch * 8];
        const ushortT* vp = (const ushortT*)&vv;
        #pragma unroll
        for (int e = 0; e < 8; ++e) V_t[wave][(ch * 8 + e) * 72 + row] = vp[e];
    }
    attn_wave_work<64, 40, 72, 72>(QKb, Ob, K_lds[wave], V_t[wave], P_lds[wave], base, 256, h, 0);
}

// ---------------- residual + LayerNorm ----------------
__global__ __launch_bounds__(256) void ln_kernel(float* __restrict__ X, const ushortT* __restrict__ Y,
                                                 const float* __restrict__ g, const float* __restrict__ be,
                                                 ushortT* __restrict__ Xb) {
    int tok = blockIdx.x * 4 + (threadIdx.x >> 6);
    int lane = threadIdx.x & 63;
    float4 x = *(float4*)&X[(size_t)tok * C_DIM + lane * 4];
    const uint2 yu = *(const uint2*)&Y[(size_t)tok * C_DIM + lane * 4];
    float v0 = x.x + bflo(yu.x), v1 = x.y + bfhi(yu.x);
    float v2 = x.z + bflo(yu.y), v3 = x.w + bfhi(yu.y);
    float s = v0 + v1 + v2 + v3;
    float ss = v0 * v0 + v1 * v1 + v2 * v2 + v3 * v3;
    #pragma unroll
    for (int off = 32; off; off >>= 1) {
        s += __shfl_xor(s, off, 64);
        ss += __shfl_xor(ss, off, 64);
    }
    float mean = s * (1.0f / 256.0f);
    float var = ss * (1.0f / 256.0f) - mean * mean;
    float inv = rsqrtf(var + LN_EPS);
    const float4 gv = *(const float4*)&g[lane * 4];
    const float4 bv = *(const float4*)&be[lane * 4];
    float o0 = (v0 - mean) * inv * gv.x + bv.x;
    float o1 = (v1 - mean) * inv * gv.y + bv.y;
    float o2 = (v2 - mean) * inv * gv.z + bv.z;
    float o3 = (v3 - mean) * inv * gv.w + bv.w;
    float4 of = {o0, o1, o2, o3};
    *(float4*)&X[(size_t)tok * C_DIM + lane * 4] = of;
    uint2 ob = {packbf(o0, o1), packbf(o2, o3)};
    *(uint2*)&Xb[(size_t)tok * C_DIM + lane * 4] = ob;
}

// ---------------- scatter back + residual ----------------
__global__ void scatter_kernel(const float* __restrict__ backbone, const float* __restrict__ X,
                               float* __restrict__ out) {
    int tok = blockIdx.x;
    int b = tok >> 14;
    int vt = tok & 16383;
    int v = vt >> 8, t = vt & 255;
    int i = v >> 3, j = v & 7, ty = t >> 4, tx = t & 15;
    int c = threadIdx.x;
    int gi = b * 4194304 + c * 16384 + (i * 16 + ty) * 128 + (j * 16 + tx);
    out[gi] = backbone[gi] + X[(size_t)tok * C_DIM + c];
}

// ---------------- defe mask ----------------
__global__ void mask_kernel(const float* __restrict__ defe, float* __restrict__ out) {
    int idx = threadIdx.x;
    if (idx >= 128) return;
    int b = idx >> 6;
    int ii = (idx >> 3) & 7;
    int jj = idx & 7;
    float mx = -1e30f;
    for (int y = 0; y < 16; ++y)
        for (int x = 0; x < 16; ++x)
            mx = fmaxf(mx, defe[b * 16384 + (ii * 16 + y) * 128 + (jj * 16 + x)]);
    out[8388608 + idx] = (mx > 0.0f) ? 1.0f : 0.0f;
}

extern "C" void kernel_launch(void* const* d_in, const int* in_sizes, int n_in,
                              void* d_out, int out_size, void* d_ws, size_t ws_size,
                              hipStream_t stream) {
    const float* backbone = (const float*)d_in[0];
    const float* defe     = (const float*)d_in[1];
    const float* glob     = (const float*)d_in[2];
    const float* Wqkv     = (const float*)d_in[3];
    const float* bqkv     = (const float*)d_in[4];
    const float* Wo       = (const float*)d_in[5];
    const float* bo       = (const float*)d_in[6];
    const float* W1       = (const float*)d_in[7];
    const float* b1       = (const float*)d_in[8];
    const float* W2       = (const float*)d_in[9];
    const float* b2       = (const float*)d_in[10];
    const float* g1       = (const float*)d_in[11];
    const float* be1      = (const float*)d_in[12];
    const float* g2       = (const float*)d_in[13];
    const float* be2      = (const float*)d_in[14];
    const float* relW1    = (const float*)d_in[15];
    const float* relb1    = (const float*)d_in[16];
    const float* relW2    = (const float*)d_in[17];
    const float* relb2    = (const float*)d_in[18];

    // workspace layout (ushort units for bf16, then fp32 Xf)
    ushortT* peb    = (ushortT*)d_ws;                       //  4,194,304
    ushortT* Wqkv_b = peb + 4194304;                        //    196,608
    ushortT* Wo_b   = Wqkv_b + 196608;                      //     65,536
    ushortT* W1_b   = Wo_b + 65536;                         //    262,144
    ushortT* W2_b   = W1_b + 262144;                        //    262,144
    ushortT* Xb     = W2_b + 262144;                        //  8,388,608
    ushortT* QKb    = Xb + 8388608;                         // 16,777,216
    ushortT* Vb     = QKb + 16777216;                       //  8,388,608
    ushortT* Ob     = Vb + 8388608;                         //  8,388,608
    ushortT* Hb     = QKb;                                  // FFN hidden aliases QK|V|O
    ushortT* Yb     = Ob + 8388608;                         //  8,388,608
    float*   Xf     = (float*)(Yb + 8388608);               //  8,388,608 floats
    size_t needed = (size_t)((char*)(Xf + 8388608) - (char*)d_ws);
    if (ws_size < needed) return;

    cvt_kernel<<<(196608 + 255) / 256, 256, 0, stream>>>(Wqkv, Wqkv_b, 196608);
    cvt_kernel<<<(65536 + 255) / 256, 256, 0, stream>>>(Wo, Wo_b, 65536);
    cvt_kernel<<<(262144 + 255) / 256, 256, 0, stream>>>(W1, W1_b, 262144);
    cvt_kernel<<<(262144 + 255) / 256, 256, 0, stream>>>(W2, W2_b, 262144);

    build_pe_kernel<<<PETOK, 256, 0, stream>>>(glob, relW1, relb1, relW2, relb2, peb);
    window_kernel<<<NTOK, 256, 0, stream>>>(backbone, Xf, Xb);

    for (int pass = 0; pass < 2; ++pass) {
        gemm_bf16<true, false><<<dim3(512 / BN, NTOK / BM), 256, 0, stream>>>(
            Xb, C_DIM, peb, Wqkv_b, bqkv, QKb, 512, C_DIM);
        gemm_bf16<false, false><<<dim3(256 / BN, NTOK / BM), 256, 0, stream>>>(
            Xb, C_DIM, nullptr, Wqkv_b + 512 * 256, bqkv + 512, Vb, C_DIM, C_DIM);
        if (pass == 0) {
            attn_p0<<<128 * NHEAD, 256, 0, stream>>>(QKb, Vb, Ob);
        } else {
            attn_p1<<<4096 / 4, 256, 0, stream>>>(QKb, Vb, Ob);
        }
        gemm_bf16<false, false><<<dim3(256 / BN, NTOK / BM), 256, 0, stream>>>(
            Ob, C_DIM, nullptr, Wo_b, bo, Yb, C_DIM, C_DIM);
        ln_kernel<<<NTOK / 4, 256, 0, stream>>>(Xf, Yb, g1, be1, Xb);
        gemm_bf16<false, true><<<dim3(DFF_DIM / BN, NTOK / BM), 256, 0, stream>>>(
            Xb, C_DIM, nullptr, W1_b, b1, Hb, DFF_DIM, C_DIM);
        gemm_bf16<false, false><<<dim3(256 / BN, NTOK / BM), 256, 0, stream>>>(
            Hb, DFF_DIM, nullptr, W2_b, b2, Yb, C_DIM, DFF_DIM);
        ln_kernel<<<NTOK / 4, 256, 0, stream>>>(Xf, Yb, g2, be2, Xb);
    }

    scatter_kernel<<<NTOK, 256, 0, stream>>>(backbone, Xf, (float*)d_out);
    mask_kernel<<<1, 128, 0, stream>>>(defe, (float*)d_out);
}

// Round 4
// 435.608 us; speedup vs baseline: 4.8416x; 1.5693x over previous
//
#include <hip/hip_runtime.h>
#include <hip/hip_bf16.h>

#define C_DIM 256
#define NHEAD 8
#define DH 32
#define NTOK 32768   // B * Nv * hw
#define PETOK 16384  // Nv * hw
#define DFF_DIM 1024
#define LN_EPS 1e-5f

typedef unsigned int u32;
typedef unsigned short ushortT;
using frag_ab = __attribute__((ext_vector_type(8))) short;
using f32x4   = __attribute__((ext_vector_type(4))) float;

__device__ __forceinline__ float bflo(u32 u) { union { u32 i; float f; } c; c.i = u << 16; return c.f; }
__device__ __forceinline__ float bfhi(u32 u) { union { u32 i; float f; } c; c.i = u & 0xffff0000u; return c.f; }
__device__ __forceinline__ ushortT f2b(float f) {
    __hip_bfloat16 b = __float2bfloat16(f);
    return *reinterpret_cast<ushortT*>(&b);
}
__device__ __forceinline__ u32 packbf(float lo, float hi) {
    return (u32)f2b(lo) | ((u32)f2b(hi) << 16);
}

// ---------------- fp32 -> bf16 converter (weights) ----------------
__global__ void cvt_kernel(const float* __restrict__ src, ushortT* __restrict__ dst, int n) {
    int i = blockIdx.x * 256 + threadIdx.x;
    if (i < n) dst[i] = f2b(src[i]);
}

// ---------------- rel-pos MLP -> rel[t][c] fp32 ----------------
__global__ void rel_kernel(const float* __restrict__ relW1, const float* __restrict__ relb1,
                           const float* __restrict__ relW2, const float* __restrict__ relb2,
                           float* __restrict__ rel) {
    __shared__ float hid[64];
    int t = blockIdx.x;                  // 0..255
    int ty = t >> 4, tx = t & 15;
    float cx = tx * (1.0f / 15.0f);
    float cy = ty * (1.0f / 15.0f);
    int c = threadIdx.x;
    if (c < 64) {
        float h = relW1[c * 2 + 0] * cx + relW1[c * 2 + 1] * cy + relb1[c];
        hid[c] = fmaxf(h, 0.0f);
    }
    __syncthreads();
    float acc = relb2[c];
    #pragma unroll
    for (int jj = 0; jj < 64; ++jj) acc = fmaf(hid[jj], relW2[c * 64 + jj], acc);
    rel[t * C_DIM + c] = acc;
}

// ---------------- pe (bf16): coalesced glob read + LDS transpose + rel add ----------------
// grid (128 y, 8 c-chunks); block 256.
__global__ __launch_bounds__(256) void pe_kernel(const float* __restrict__ glob,
                                                 const float* __restrict__ rel,
                                                 ushortT* __restrict__ peb) {
    __shared__ float tile[32][129];
    const int y = blockIdx.x;
    const int c0 = blockIdx.y * 32;
    const int i = y >> 4, ty = y & 15;
    const int tid = threadIdx.x;
    const int xl = tid & 127;
    #pragma unroll
    for (int p = 0; p < 16; ++p) {
        const int cl = p * 2 + (tid >> 7);
        tile[cl][xl] = glob[(size_t)(c0 + cl) * 16384 + y * 128 + xl];
    }
    __syncthreads();
    const int cl = tid & 31;
    #pragma unroll
    for (int p = 0; p < 16; ++p) {
        const int x = p * 8 + (tid >> 5);
        const int v = i * 8 + (x >> 4);
        const int t = ty * 16 + (x & 15);
        const float val = tile[cl][x] + rel[t * C_DIM + c0 + cl];
        peb[(size_t)(v * 256 + t) * C_DIM + c0 + cl] = f2b(val);
    }
}

// ---------------- window partition: coalesced read + transpose -> Xf/Xb ----------------
// grid (128 y, 8 c-chunks, B); block 256.
__global__ __launch_bounds__(256) void window_kernel(const float* __restrict__ backbone,
                                                     float* __restrict__ Xf, ushortT* __restrict__ Xb) {
    __shared__ float tile[32][129];
    const int y = blockIdx.x;
    const int c0 = blockIdx.y * 32;
    const int b = blockIdx.z;
    const int i = y >> 4, ty = y & 15;
    const int tid = threadIdx.x;
    const int xl = tid & 127;
    #pragma unroll
    for (int p = 0; p < 16; ++p) {
        const int cl = p * 2 + (tid >> 7);
        tile[cl][xl] = backbone[(size_t)b * 4194304 + (size_t)(c0 + cl) * 16384 + y * 128 + xl];
    }
    __syncthreads();
    const int cl = tid & 31;
    #pragma unroll
    for (int p = 0; p < 16; ++p) {
        const int x = p * 8 + (tid >> 5);
        const int v = i * 8 + (x >> 4);
        const int t = ty * 16 + (x & 15);
        const size_t tok = (size_t)b * PETOK + v * 256 + t;
        const float val = tile[cl][x];
        Xf[tok * C_DIM + c0 + cl] = val;
        Xb[tok * C_DIM + c0 + cl] = f2b(val);
    }
}

// ---------------- scatter back + residual: transpose + coalesced write ----------------
// grid (128 y, 8 c-chunks, B); block 256.
__global__ __launch_bounds__(256) void scatter_kernel(const float* __restrict__ backbone,
                                                      const float* __restrict__ X,
                                                      float* __restrict__ out) {
    __shared__ float tile[128][33];
    const int y = blockIdx.x;
    const int c0 = blockIdx.y * 32;
    const int b = blockIdx.z;
    const int i = y >> 4, ty = y & 15;
    const int tid = threadIdx.x;
    const int cl = tid & 31;
    #pragma unroll
    for (int p = 0; p < 16; ++p) {
        const int x = p * 8 + (tid >> 5);
        const int v = i * 8 + (x >> 4);
        const int t = ty * 16 + (x & 15);
        const size_t tok = (size_t)b * PETOK + v * 256 + t;
        tile[x][cl] = X[tok * C_DIM + c0 + cl];
    }
    __syncthreads();
    const int xl = tid & 127;
    #pragma unroll
    for (int p = 0; p < 16; ++p) {
        const int c = c0 + p * 2 + (tid >> 7);
        const size_t gi = (size_t)b * 4194304 + (size_t)c * 16384 + y * 128 + xl;
        out[gi] = backbone[gi] + tile[xl][p * 2 + (tid >> 7)];
    }
}

// ---------------- bf16 MFMA GEMM: C = A * W^T + bias ----------------
#define BM 128
#define BN 128
#define BK 32
#define LDT 40   // padded LDS stride (bf16 elems)

template<bool FUSE_PE, bool RELU>
__global__ __launch_bounds__(256) void gemm_bf16(
        const ushortT* __restrict__ A, int lda,
        const ushortT* __restrict__ peb,
        const ushortT* __restrict__ W,
        const float* __restrict__ bias,
        ushortT* __restrict__ Cout, int ldc, int K) {
    __shared__ ushortT As[BM][LDT];
    __shared__ ushortT Bs[BN][LDT];
    const int m0 = blockIdx.y * BM;
    const int n0 = blockIdx.x * BN;
    const int tid = threadIdx.x;
    const int lane = tid & 63;
    const int wave = tid >> 6;
    const int wm = (wave >> 1) * 64;
    const int wn = (wave & 1) * 64;
    const int fr = lane & 15;
    const int fg = lane >> 4;
    const int sRow = tid >> 2;
    const int sCol = (tid & 3) * 8;

    f32x4 acc[4][4];
    #pragma unroll
    for (int i = 0; i < 4; ++i)
        #pragma unroll
        for (int j = 0; j < 4; ++j)
            acc[i][j] = (f32x4){0.f, 0.f, 0.f, 0.f};

    for (int k0 = 0; k0 < K; k0 += BK) {
        #pragma unroll
        for (int h = 0; h < 2; ++h) {
            const int row = sRow + h * 64;
            uint4 av = *(const uint4*)&A[(size_t)(m0 + row) * lda + k0 + sCol];
            if (FUSE_PE) {
                const uint4 pv = *(const uint4*)&peb[(size_t)((m0 + row) & 16383) * C_DIM + k0 + sCol];
                u32* a = (u32*)&av;
                const u32* p = (const u32*)&pv;
                #pragma unroll
                for (int e = 0; e < 4; ++e)
                    a[e] = packbf(bflo(a[e]) + bflo(p[e]), bfhi(a[e]) + bfhi(p[e]));
            }
            *(uint4*)&As[row][sCol] = av;
            const uint4 bv = *(const uint4*)&W[(size_t)(n0 + row) * K + k0 + sCol];
            *(uint4*)&Bs[row][sCol] = bv;
        }
        __syncthreads();
        frag_ab af[4], bf[4];
        #pragma unroll
        for (int i = 0; i < 4; ++i) af[i] = *(const frag_ab*)&As[wm + i * 16 + fr][fg * 8];
        #pragma unroll
        for (int j = 0; j < 4; ++j) bf[j] = *(const frag_ab*)&Bs[wn + j * 16 + fr][fg * 8];
        #pragma unroll
        for (int i = 0; i < 4; ++i)
            #pragma unroll
            for (int j = 0; j < 4; ++j)
                acc[i][j] = __builtin_amdgcn_mfma_f32_16x16x32_bf16(af[i], bf[j], acc[i][j], 0, 0, 0);
        __syncthreads();
    }
    #pragma unroll
    for (int j = 0; j < 4; ++j) {
        const float bv = bias[n0 + wn + j * 16 + fr];
        #pragma unroll
        for (int i = 0; i < 4; ++i) {
            #pragma unroll
            for (int r = 0; r < 4; ++r) {
                float v = acc[i][j][r] + bv;
                if (RELU) v = fmaxf(v, 0.0f);
                const int m = m0 + wm + i * 16 + fg * 4 + r;
                const int n = n0 + wn + j * 16 + fr;
                Cout[(size_t)m * ldc + n] = f2b(v);
            }
        }
    }
}

// ---------------- MFMA flash attention ----------------
template<int S, int LDK, int LDV, int LDP>
__device__ __forceinline__ void attn_wave_work(
        const ushortT* __restrict__ QKb, ushortT* __restrict__ Ob,
        const ushortT* __restrict__ K_lds, const ushortT* __restrict__ V_t,
        ushortT* __restrict__ P_lds,
        int base, int seqStride, int head, int q0base) {
    constexpr int NKT = S / 16;
    constexpr int NKC = S / 32;
    const int lane = threadIdx.x & 63;
    const int fr = lane & 15;
    const int fg = lane >> 4;
    const float scale = 0.17677669529663687f;   // 1/sqrt(32)
    #pragma unroll
    for (int s = 0; s < 4; ++s) {
        const int qq = q0base + s * 16 + fr;
        const size_t qtok = (size_t)(base + qq * seqStride);
        const frag_ab qf = *(const frag_ab*)&QKb[qtok * 512 + head * DH + fg * 8];
        f32x4 sc[NKT];
        #pragma unroll
        for (int kt = 0; kt < NKT; ++kt) {
            const frag_ab kf = *(const frag_ab*)&K_lds[(kt * 16 + fr) * LDK + fg * 8];
            sc[kt] = __builtin_amdgcn_mfma_f32_16x16x32_bf16(kf, qf, (f32x4){0.f, 0.f, 0.f, 0.f}, 0, 0, 0);
        }
        float mx = -1e30f;
        #pragma unroll
        for (int kt = 0; kt < NKT; ++kt)
            mx = fmaxf(mx, fmaxf(fmaxf(sc[kt][0], sc[kt][1]), fmaxf(sc[kt][2], sc[kt][3])));
        mx = fmaxf(mx, __shfl_xor(mx, 16, 64));
        mx = fmaxf(mx, __shfl_xor(mx, 32, 64));
        float lsum = 0.f;
        #pragma unroll
        for (int kt = 0; kt < NKT; ++kt) {
            const float p0 = __expf((sc[kt][0] - mx) * scale);
            const float p1 = __expf((sc[kt][1] - mx) * scale);
            const float p2 = __expf((sc[kt][2] - mx) * scale);
            const float p3 = __expf((sc[kt][3] - mx) * scale);
            lsum += (p0 + p1) + (p2 + p3);
            uint2 pk;
            pk.x = packbf(p0, p1);
            pk.y = packbf(p2, p3);
            *(uint2*)&P_lds[fr * LDP + kt * 16 + fg * 4] = pk;
        }
        lsum += __shfl_xor(lsum, 16, 64);
        lsum += __shfl_xor(lsum, 32, 64);
        f32x4 o0 = {0.f, 0.f, 0.f, 0.f}, o1 = {0.f, 0.f, 0.f, 0.f};
        #pragma unroll
        for (int kc = 0; kc < NKC; ++kc) {
            const frag_ab pf = *(const frag_ab*)&P_lds[fr * LDP + kc * 32 + fg * 8];
            const frag_ab v0 = *(const frag_ab*)&V_t[fr * LDV + kc * 32 + fg * 8];
            const frag_ab v1 = *(const frag_ab*)&V_t[(16 + fr) * LDV + kc * 32 + fg * 8];
            o0 = __builtin_amdgcn_mfma_f32_16x16x32_bf16(v0, pf, o0, 0, 0, 0);
            o1 = __builtin_amdgcn_mfma_f32_16x16x32_bf16(v1, pf, o1, 0, 0, 0);
        }
        const float inv = 1.0f / lsum;
        ushortT* ob = &Ob[qtok * C_DIM + head * DH];
        uint2 w0, w1;
        w0.x = packbf(o0[0] * inv, o0[1] * inv);
        w0.y = packbf(o0[2] * inv, o0[3] * inv);
        w1.x = packbf(o1[0] * inv, o1[1] * inv);
        w1.y = packbf(o1[2] * inv, o1[3] * inv);
        *(uint2*)&ob[fg * 4] = w0;
        *(uint2*)&ob[16 + fg * 4] = w1;
    }
}

// pass 0: block = (b, v, head); 4 waves share K/V_t, each owns 64 queries
__global__ __launch_bounds__(256) void attn_p0(const ushortT* __restrict__ QKb,
                                               const ushortT* __restrict__ Vb,
                                               ushortT* __restrict__ Ob) {
    __shared__ ushortT K_lds[256 * 40];
    __shared__ ushortT V_t[32 * 272];
    __shared__ ushortT P_lds[4][16 * 264];
    const int grp = blockIdx.x;
    const int h = grp & 7;
    const int bv = grp >> 3;
    const int base = (bv >> 6) * PETOK + (bv & 63) * 256;
    const int tid = threadIdx.x;
    #pragma unroll
    for (int it = 0; it < 4; ++it) {
        const int idx = it * 256 + tid;
        const int row = idx >> 2, ch = idx & 3;
        const size_t tok = (size_t)(base + row);
        const uint4 kv = *(const uint4*)&QKb[tok * 512 + 256 + h * DH + ch * 8];
        *(uint4*)&K_lds[row * 40 + ch * 8] = kv;
        const uint4 vv = *(const uint4*)&Vb[tok * C_DIM + h * DH + ch * 8];
        const ushortT* vp = (const ushortT*)&vv;
        #pragma unroll
        for (int e = 0; e < 8; ++e) V_t[(ch * 8 + e) * 272 + row] = vp[e];
    }
    __syncthreads();
    const int wave = tid >> 6;
    attn_wave_work<256, 40, 272, 264>(QKb, Ob, K_lds, V_t, P_lds[wave], base, 1, h, wave * 64);
}

// pass 1: 4 independent waves per block, wave = one (b, t, head), S=64
__global__ __launch_bounds__(256) void attn_p1(const ushortT* __restrict__ QKb,
                                               const ushortT* __restrict__ Vb,
                                               ushortT* __restrict__ Ob) {
    __shared__ ushortT K_lds[4][64 * 40];
    __shared__ ushortT V_t[4][32 * 72];
    __shared__ ushortT P_lds[4][16 * 72];
    const int wave = threadIdx.x >> 6;
    const int lane = threadIdx.x & 63;
    const int unit = blockIdx.x * 4 + wave;
    const int h = unit & 7;
    const int g = unit >> 3;
    const int base = (g >> 8) * PETOK + (g & 255);
    #pragma unroll
    for (int it = 0; it < 4; ++it) {
        const int idx = it * 64 + lane;
        const int row = idx >> 2, ch = idx & 3;
        const size_t tok = (size_t)(base + row * 256);
        const uint4 kv = *(const uint4*)&QKb[tok * 512 + 256 + h * DH + ch * 8];
        *(uint4*)&K_lds[wave][row * 40 + ch * 8] = kv;
        const uint4 vv = *(const uint4*)&Vb[tok * C_DIM + h * DH + ch * 8];
        const ushortT* vp = (const ushortT*)&vv;
        #pragma unroll
        for (int e = 0; e < 8; ++e) V_t[wave][(ch * 8 + e) * 72 + row] = vp[e];
    }
    attn_wave_work<64, 40, 72, 72>(QKb, Ob, K_lds[wave], V_t[wave], P_lds[wave], base, 256, h, 0);
}

// ---------------- residual + LayerNorm ----------------
__global__ __launch_bounds__(256) void ln_kernel(float* __restrict__ X, const ushortT* __restrict__ Y,
                                                 const float* __restrict__ g, const float* __restrict__ be,
                                                 ushortT* __restrict__ Xb) {
    int tok = blockIdx.x * 4 + (threadIdx.x >> 6);
    int lane = threadIdx.x & 63;
    float4 x = *(float4*)&X[(size_t)tok * C_DIM + lane * 4];
    const uint2 yu = *(const uint2*)&Y[(size_t)tok * C_DIM + lane * 4];
    float v0 = x.x + bflo(yu.x), v1 = x.y + bfhi(yu.x);
    float v2 = x.z + bflo(yu.y), v3 = x.w + bfhi(yu.y);
    float s = v0 + v1 + v2 + v3;
    float ss = v0 * v0 + v1 * v1 + v2 * v2 + v3 * v3;
    #pragma unroll
    for (int off = 32; off; off >>= 1) {
        s += __shfl_xor(s, off, 64);
        ss += __shfl_xor(ss, off, 64);
    }
    float mean = s * (1.0f / 256.0f);
    float var = ss * (1.0f / 256.0f) - mean * mean;
    float inv = rsqrtf(var + LN_EPS);
    const float4 gv = *(const float4*)&g[lane * 4];
    const float4 bv = *(const float4*)&be[lane * 4];
    float o0 = (v0 - mean) * inv * gv.x + bv.x;
    float o1 = (v1 - mean) * inv * gv.y + bv.y;
    float o2 = (v2 - mean) * inv * gv.z + bv.z;
    float o3 = (v3 - mean) * inv * gv.w + bv.w;
    float4 of = {o0, o1, o2, o3};
    *(float4*)&X[(size_t)tok * C_DIM + lane * 4] = of;
    uint2 ob = {packbf(o0, o1), packbf(o2, o3)};
    *(uint2*)&Xb[(size_t)tok * C_DIM + lane * 4] = ob;
}

// ---------------- defe mask: parallel maxpool ----------------
__global__ void mask_kernel(const float* __restrict__ defe, float* __restrict__ out) {
    __shared__ float wmax[4];
    const int idx = blockIdx.x;          // 0..127
    const int b = idx >> 6;
    const int ii = (idx >> 3) & 7;
    const int jj = idx & 7;
    const int t = threadIdx.x;           // 0..255: one input elem
    const int y = t >> 4, xx = t & 15;
    float v = defe[b * 16384 + (ii * 16 + y) * 128 + jj * 16 + xx];
    #pragma unroll
    for (int off = 32; off; off >>= 1) v = fmaxf(v, __shfl_xor(v, off, 64));
    if ((t & 63) == 0) wmax[t >> 6] = v;
    __syncthreads();
    if (t == 0) {
        float mx = fmaxf(fmaxf(wmax[0], wmax[1]), fmaxf(wmax[2], wmax[3]));
        out[8388608 + idx] = (mx > 0.0f) ? 1.0f : 0.0f;
    }
}

extern "C" void kernel_launch(void* const* d_in, const int* in_sizes, int n_in,
                              void* d_out, int out_size, void* d_ws, size_t ws_size,
                              hipStream_t stream) {
    const float* backbone = (const float*)d_in[0];
    const float* defe     = (const float*)d_in[1];
    const float* glob     = (const float*)d_in[2];
    const float* Wqkv     = (const float*)d_in[3];
    const float* bqkv     = (const float*)d_in[4];
    const float* Wo       = (const float*)d_in[5];
    const float* bo       = (const float*)d_in[6];
    const float* W1       = (const float*)d_in[7];
    const float* b1       = (const float*)d_in[8];
    const float* W2       = (const float*)d_in[9];
    const float* b2       = (const float*)d_in[10];
    const float* g1       = (const float*)d_in[11];
    const float* be1      = (const float*)d_in[12];
    const float* g2       = (const float*)d_in[13];
    const float* be2      = (const float*)d_in[14];
    const float* relW1    = (const float*)d_in[15];
    const float* relb1    = (const float*)d_in[16];
    const float* relW2    = (const float*)d_in[17];
    const float* relb2    = (const float*)d_in[18];

    // workspace layout
    ushortT* peb    = (ushortT*)d_ws;                       //  4,194,304
    ushortT* Wqkv_b = peb + 4194304;                        //    196,608
    ushortT* Wo_b   = Wqkv_b + 196608;                      //     65,536
    ushortT* W1_b   = Wo_b + 65536;                         //    262,144
    ushortT* W2_b   = W1_b + 262144;                        //    262,144
    ushortT* Xb     = W2_b + 262144;                        //  8,388,608
    ushortT* QKb    = Xb + 8388608;                         // 16,777,216
    ushortT* Vb     = QKb + 16777216;                       //  8,388,608
    ushortT* Ob     = Vb + 8388608;                         //  8,388,608
    ushortT* Hb     = QKb;                                  // FFN hidden aliases QK|V|O
    ushortT* Yb     = Ob + 8388608;                         //  8,388,608
    float*   Xf     = (float*)(Yb + 8388608);               //  8,388,608 floats
    float*   relf   = Xf + 8388608;                         //     65,536 floats
    size_t needed = (size_t)((char*)(relf + 65536) - (char*)d_ws);
    if (ws_size < needed) return;

    cvt_kernel<<<(196608 + 255) / 256, 256, 0, stream>>>(Wqkv, Wqkv_b, 196608);
    cvt_kernel<<<(65536 + 255) / 256, 256, 0, stream>>>(Wo, Wo_b, 65536);
    cvt_kernel<<<(262144 + 255) / 256, 256, 0, stream>>>(W1, W1_b, 262144);
    cvt_kernel<<<(262144 + 255) / 256, 256, 0, stream>>>(W2, W2_b, 262144);

    rel_kernel<<<256, 256, 0, stream>>>(relW1, relb1, relW2, relb2, relf);
    pe_kernel<<<dim3(128, 8), 256, 0, stream>>>(glob, relf, peb);
    window_kernel<<<dim3(128, 8, 2), 256, 0, stream>>>(backbone, Xf, Xb);

    for (int pass = 0; pass < 2; ++pass) {
        gemm_bf16<true, false><<<dim3(512 / BN, NTOK / BM), 256, 0, stream>>>(
            Xb, C_DIM, peb, Wqkv_b, bqkv, QKb, 512, C_DIM);
        gemm_bf16<false, false><<<dim3(256 / BN, NTOK / BM), 256, 0, stream>>>(
            Xb, C_DIM, nullptr, Wqkv_b + 512 * 256, bqkv + 512, Vb, C_DIM, C_DIM);
        if (pass == 0) {
            attn_p0<<<128 * NHEAD, 256, 0, stream>>>(QKb, Vb, Ob);
        } else {
            attn_p1<<<4096 / 4, 256, 0, stream>>>(QKb, Vb, Ob);
        }
        gemm_bf16<false, false><<<dim3(256 / BN, NTOK / BM), 256, 0, stream>>>(
            Ob, C_DIM, nullptr, Wo_b, bo, Yb, C_DIM, C_DIM);
        ln_kernel<<<NTOK / 4, 256, 0, stream>>>(Xf, Yb, g1, be1, Xb);
        gemm_bf16<false, true><<<dim3(DFF_DIM / BN, NTOK / BM), 256, 0, stream>>>(
            Xb, C_DIM, nullptr, W1_b, b1, Hb, DFF_DIM, C_DIM);
        gemm_bf16<false, false><<<dim3(256 / BN, NTOK / BM), 256, 0, stream>>>(
            Hb, DFF_DIM, nullptr, W2_b, b2, Yb, C_DIM, DFF_DIM);
        ln_kernel<<<NTOK / 4, 256, 0, stream>>>(Xf, Yb, g2, be2, Xb);
    }

    scatter_kernel<<<dim3(128, 8, 2), 256, 0, stream>>>(backbone, Xf, (float*)d_out);
    mask_kernel<<<128, 256, 0, stream>>>(defe, (float*)d_out);
}

// Round 5
// 411.294 us; speedup vs baseline: 5.1278x; 1.0591x over previous
//
#include <hip/hip_runtime.h>
#include <hip/hip_bf16.h>

#define C_DIM 256
#define NHEAD 8
#define DH 32
#define NTOK 32768   // B * Nv * hw
#define PETOK 16384  // Nv * hw
#define DFF_DIM 1024
#define LN_EPS 1e-5f

typedef unsigned int u32;
typedef unsigned short ushortT;
using frag_ab = __attribute__((ext_vector_type(8))) short;
using f32x4   = __attribute__((ext_vector_type(4))) float;

__device__ __forceinline__ float bflo(u32 u) { union { u32 i; float f; } c; c.i = u << 16; return c.f; }
__device__ __forceinline__ float bfhi(u32 u) { union { u32 i; float f; } c; c.i = u & 0xffff0000u; return c.f; }
__device__ __forceinline__ ushortT f2b(float f) {
    __hip_bfloat16 b = __float2bfloat16(f);
    return *reinterpret_cast<ushortT*>(&b);
}
__device__ __forceinline__ u32 packbf(float lo, float hi) {
    return (u32)f2b(lo) | ((u32)f2b(hi) << 16);
}
// async global->LDS, 16B per lane; LDS dest = wave-uniform base + lane*16
__device__ __forceinline__ void gload_lds16(const ushortT* g, ushortT* l) {
    __builtin_amdgcn_global_load_lds((const __attribute__((address_space(1))) void*)g,
                                     (__attribute__((address_space(3))) void*)l, 16, 0, 0);
}

// ---------------- fp32 -> bf16 weight converter (fused, 4 segments) ----------------
__global__ void cvt_all_kernel(const float* __restrict__ Wqkv, const float* __restrict__ Wo,
                               const float* __restrict__ W1, const float* __restrict__ W2,
                               ushortT* __restrict__ dst) {
    const int i = (blockIdx.x * 256 + threadIdx.x) * 4;   // 786432 elems total
    const float* src;
    int off;
    if (i < 196608)      { src = Wqkv; off = 0; }
    else if (i < 262144) { src = Wo;   off = 196608; }
    else if (i < 524288) { src = W1;   off = 262144; }
    else                 { src = W2;   off = 524288; }
    const float4 v = *(const float4*)&src[i - off];
    uint2 o = {packbf(v.x, v.y), packbf(v.z, v.w)};
    *(uint2*)&dst[i] = o;
}

// ---------------- rel-pos MLP -> rel[t][c] fp32 ----------------
__global__ void rel_kernel(const float* __restrict__ relW1, const float* __restrict__ relb1,
                           const float* __restrict__ relW2, const float* __restrict__ relb2,
                           float* __restrict__ rel) {
    __shared__ float hid[64];
    int t = blockIdx.x;                  // 0..255
    int ty = t >> 4, tx = t & 15;
    float cx = tx * (1.0f / 15.0f);
    float cy = ty * (1.0f / 15.0f);
    int c = threadIdx.x;
    if (c < 64) {
        float h = relW1[c * 2 + 0] * cx + relW1[c * 2 + 1] * cy + relb1[c];
        hid[c] = fmaxf(h, 0.0f);
    }
    __syncthreads();
    float acc = relb2[c];
    #pragma unroll
    for (int jj = 0; jj < 64; ++jj) acc = fmaf(hid[jj], relW2[c * 64 + jj], acc);
    rel[t * C_DIM + c] = acc;
}

// ---------------- pe (bf16): coalesced glob read + LDS transpose + rel add ----------------
__global__ __launch_bounds__(256) void pe_kernel(const float* __restrict__ glob,
                                                 const float* __restrict__ rel,
                                                 ushortT* __restrict__ peb) {
    __shared__ float tile[32][129];
    const int y = blockIdx.x;
    const int c0 = blockIdx.y * 32;
    const int i = y >> 4, ty = y & 15;
    const int tid = threadIdx.x;
    const int xl = tid & 127;
    #pragma unroll
    for (int p = 0; p < 16; ++p) {
        const int cl = p * 2 + (tid >> 7);
        tile[cl][xl] = glob[(size_t)(c0 + cl) * 16384 + y * 128 + xl];
    }
    __syncthreads();
    const int cl = tid & 31;
    #pragma unroll
    for (int p = 0; p < 16; ++p) {
        const int x = p * 8 + (tid >> 5);
        const int v = i * 8 + (x >> 4);
        const int t = ty * 16 + (x & 15);
        const float val = tile[cl][x] + rel[t * C_DIM + c0 + cl];
        peb[(size_t)(v * 256 + t) * C_DIM + c0 + cl] = f2b(val);
    }
}

// ---------------- window partition: coalesced read + transpose -> Xf/Xb ----------------
__global__ __launch_bounds__(256) void window_kernel(const float* __restrict__ backbone,
                                                     float* __restrict__ Xf, ushortT* __restrict__ Xb) {
    __shared__ float tile[32][129];
    const int y = blockIdx.x;
    const int c0 = blockIdx.y * 32;
    const int b = blockIdx.z;
    const int i = y >> 4, ty = y & 15;
    const int tid = threadIdx.x;
    const int xl = tid & 127;
    #pragma unroll
    for (int p = 0; p < 16; ++p) {
        const int cl = p * 2 + (tid >> 7);
        tile[cl][xl] = backbone[(size_t)b * 4194304 + (size_t)(c0 + cl) * 16384 + y * 128 + xl];
    }
    __syncthreads();
    const int cl = tid & 31;
    #pragma unroll
    for (int p = 0; p < 16; ++p) {
        const int x = p * 8 + (tid >> 5);
        const int v = i * 8 + (x >> 4);
        const int t = ty * 16 + (x & 15);
        const size_t tok = (size_t)b * PETOK + v * 256 + t;
        const float val = tile[cl][x];
        Xf[tok * C_DIM + c0 + cl] = val;
        Xb[tok * C_DIM + c0 + cl] = f2b(val);
    }
}

// ---------------- scatter back + residual: transpose + coalesced write ----------------
__global__ __launch_bounds__(256) void scatter_kernel(const float* __restrict__ backbone,
                                                      const float* __restrict__ X,
                                                      float* __restrict__ out) {
    __shared__ float tile[128][33];
    const int y = blockIdx.x;
    const int c0 = blockIdx.y * 32;
    const int b = blockIdx.z;
    const int i = y >> 4, ty = y & 15;
    const int tid = threadIdx.x;
    const int cl = tid & 31;
    #pragma unroll
    for (int p = 0; p < 16; ++p) {
        const int x = p * 8 + (tid >> 5);
        const int v = i * 8 + (x >> 4);
        const int t = ty * 16 + (x & 15);
        const size_t tok = (size_t)b * PETOK + v * 256 + t;
        tile[x][cl] = X[tok * C_DIM + c0 + cl];
    }
    __syncthreads();
    const int xl = tid & 127;
    #pragma unroll
    for (int p = 0; p < 16; ++p) {
        const int c = c0 + p * 2 + (tid >> 7);
        const size_t gi = (size_t)b * 4194304 + (size_t)c * 16384 + y * 128 + xl;
        out[gi] = backbone[gi] + tile[xl][p * 2 + (tid >> 7)];
    }
}

// ---------------- bf16 MFMA GEMM (m97 structure): C = A * W^T + bias ----------------
// Linear LDS [128][32]; B (and A when !FUSE_PE) staged via global_load_lds width=16.
#define BM 128
#define BN 128
#define BK 32

template<bool FUSE_PE, bool RELU>
__global__ __launch_bounds__(256) void gemm_bf16(
        const ushortT* __restrict__ A, int lda,
        const ushortT* __restrict__ peb,
        const ushortT* __restrict__ W,
        const float* __restrict__ bias,
        ushortT* __restrict__ Cout, int ldc, int K) {
    __shared__ ushortT As[BM][BK];
    __shared__ ushortT Bs[BN][BK];
    const int m0 = blockIdx.y * BM;
    const int n0 = blockIdx.x * BN;
    const int tid = threadIdx.x;
    const int lane = tid & 63;
    const int wave = tid >> 6;
    const int wm = (wave >> 1) * 64;
    const int wn = (wave & 1) * 64;
    const int fr = lane & 15;
    const int fg = lane >> 4;
    // global_load_lds staging: wave stages rows wave*32 + {0..15, 16..31}
    const int gRow = wave * 32 + (lane >> 2);
    const int gCol = (lane & 3) * 8;
    // reg-staging coords (FUSE_PE A path)
    const int sRow = tid >> 2;
    const int sCol = (tid & 3) * 8;

    f32x4 acc[4][4];
    #pragma unroll
    for (int i = 0; i < 4; ++i)
        #pragma unroll
        for (int j = 0; j < 4; ++j)
            acc[i][j] = (f32x4){0.f, 0.f, 0.f, 0.f};

    for (int k0 = 0; k0 < K; k0 += BK) {
        if (FUSE_PE) {
            #pragma unroll
            for (int h = 0; h < 2; ++h) {
                const int row = sRow + h * 64;
                uint4 av = *(const uint4*)&A[(size_t)(m0 + row) * lda + k0 + sCol];
                const uint4 pv = *(const uint4*)&peb[(size_t)((m0 + row) & 16383) * C_DIM + k0 + sCol];
                u32* a = (u32*)&av;
                const u32* p = (const u32*)&pv;
                #pragma unroll
                for (int e = 0; e < 4; ++e)
                    a[e] = packbf(bflo(a[e]) + bflo(p[e]), bfhi(a[e]) + bfhi(p[e]));
                *(uint4*)&As[row][sCol] = av;
            }
        } else {
            gload_lds16(&A[(size_t)(m0 + gRow) * lda + k0 + gCol], &As[wave * 32][0]);
            gload_lds16(&A[(size_t)(m0 + gRow + 16) * lda + k0 + gCol], &As[wave * 32 + 16][0]);
        }
        gload_lds16(&W[(size_t)(n0 + gRow) * K + k0 + gCol], &Bs[wave * 32][0]);
        gload_lds16(&W[(size_t)(n0 + gRow + 16) * K + k0 + gCol], &Bs[wave * 32 + 16][0]);
        __syncthreads();
        frag_ab af[4], bf[4];
        #pragma unroll
        for (int i = 0; i < 4; ++i) af[i] = *(const frag_ab*)&As[wm + i * 16 + fr][fg * 8];
        #pragma unroll
        for (int j = 0; j < 4; ++j) bf[j] = *(const frag_ab*)&Bs[wn + j * 16 + fr][fg * 8];
        #pragma unroll
        for (int i = 0; i < 4; ++i)
            #pragma unroll
            for (int j = 0; j < 4; ++j)
                acc[i][j] = __builtin_amdgcn_mfma_f32_16x16x32_bf16(af[i], bf[j], acc[i][j], 0, 0, 0);
        __syncthreads();
    }
    #pragma unroll
    for (int j = 0; j < 4; ++j) {
        const float bv = bias[n0 + wn + j * 16 + fr];
        #pragma unroll
        for (int i = 0; i < 4; ++i) {
            #pragma unroll
            for (int r = 0; r < 4; ++r) {
                float v = acc[i][j][r] + bv;
                if (RELU) v = fmaxf(v, 0.0f);
                const int m = m0 + wm + i * 16 + fg * 4 + r;
                const int n = n0 + wn + j * 16 + fr;
                Cout[(size_t)m * ldc + n] = f2b(v);
            }
        }
    }
}

// ---------------- attn pass 0: flash over 2 KV-chunks of 128, online softmax ----------------
// block = (b, v, head); 4 waves, each owns 64 queries (4 tiles of 16).
#define KVC 128
__global__ __launch_bounds__(256) void attn_p0(const ushortT* __restrict__ QKb,
                                               const ushortT* __restrict__ Vb,
                                               ushortT* __restrict__ Ob) {
    __shared__ ushortT K_lds[KVC * 40];      // 10.0 KB
    __shared__ ushortT V_t[32 * 136];        //  8.5 KB
    __shared__ ushortT P_lds[4][16 * 136];   // 17.0 KB
    const int grp = blockIdx.x;              // (b*64+v)*8 + h
    const int h = grp & 7;
    const int bv = grp >> 3;
    const int base = (bv >> 6) * PETOK + (bv & 63) * 256;
    const int tid = threadIdx.x;
    const int wave = tid >> 6;
    const int lane = tid & 63;
    const int fr = lane & 15;
    const int fg = lane >> 4;
    const float scale = 0.17677669529663687f;   // 1/sqrt(32)

    // Q fragments for this wave's 4 query tiles (held in registers)
    frag_ab qf[4];
    size_t qtok[4];
    #pragma unroll
    for (int s = 0; s < 4; ++s) {
        qtok[s] = (size_t)(base + wave * 64 + s * 16 + fr);
        qf[s] = *(const frag_ab*)&QKb[qtok[s] * 512 + h * DH + fg * 8];
    }
    float m[4], l[4];
    f32x4 o0[4], o1[4];
    #pragma unroll
    for (int s = 0; s < 4; ++s) {
        m[s] = -1e30f; l[s] = 0.f;
        o0[s] = (f32x4){0.f, 0.f, 0.f, 0.f};
        o1[s] = (f32x4){0.f, 0.f, 0.f, 0.f};
    }

    for (int c = 0; c < 2; ++c) {
        __syncthreads();                     // all waves done with previous chunk
        #pragma unroll
        for (int it = 0; it < 2; ++it) {
            const int idx = it * 256 + tid;  // 0..511
            const int row = idx >> 2, ch = idx & 3;
            const size_t tok = (size_t)(base + c * KVC + row);
            const uint4 kv = *(const uint4*)&QKb[tok * 512 + 256 + h * DH + ch * 8];
            *(uint4*)&K_lds[row * 40 + ch * 8] = kv;
            const uint4 vv = *(const uint4*)&Vb[tok * C_DIM + h * DH + ch * 8];
            const ushortT* vp = (const ushortT*)&vv;
            #pragma unroll
            for (int e = 0; e < 8; ++e) V_t[(ch * 8 + e) * 136 + row] = vp[e];
        }
        __syncthreads();
        #pragma unroll
        for (int s = 0; s < 4; ++s) {
            f32x4 sc[8];
            #pragma unroll
            for (int kt = 0; kt < 8; ++kt) {
                const frag_ab kf = *(const frag_ab*)&K_lds[(kt * 16 + fr) * 40 + fg * 8];
                sc[kt] = __builtin_amdgcn_mfma_f32_16x16x32_bf16(kf, qf[s], (f32x4){0.f, 0.f, 0.f, 0.f}, 0, 0, 0);
            }
            float mx = -1e30f;
            #pragma unroll
            for (int kt = 0; kt < 8; ++kt)
                mx = fmaxf(mx, fmaxf(fmaxf(sc[kt][0], sc[kt][1]), fmaxf(sc[kt][2], sc[kt][3])));
            mx = fmaxf(mx, __shfl_xor(mx, 16, 64));
            mx = fmaxf(mx, __shfl_xor(mx, 32, 64));
            const float nm = fmaxf(m[s], mx);
            const float corr = __expf((m[s] - nm) * scale);
            m[s] = nm;
            float lsum = 0.f;
            #pragma unroll
            for (int kt = 0; kt < 8; ++kt) {
                const float p0 = __expf((sc[kt][0] - nm) * scale);
                const float p1 = __expf((sc[kt][1] - nm) * scale);
                const float p2 = __expf((sc[kt][2] - nm) * scale);
                const float p3 = __expf((sc[kt][3] - nm) * scale);
                lsum += (p0 + p1) + (p2 + p3);
                uint2 pk;
                pk.x = packbf(p0, p1);
                pk.y = packbf(p2, p3);
                *(uint2*)&P_lds[wave][fr * 136 + kt * 16 + fg * 4] = pk;
            }
            lsum += __shfl_xor(lsum, 16, 64);
            lsum += __shfl_xor(lsum, 32, 64);
            l[s] = l[s] * corr + lsum;
            o0[s] *= corr;
            o1[s] *= corr;
            #pragma unroll
            for (int kc = 0; kc < 4; ++kc) {
                const frag_ab pf = *(const frag_ab*)&P_lds[wave][fr * 136 + kc * 32 + fg * 8];
                const frag_ab v0 = *(const frag_ab*)&V_t[fr * 136 + kc * 32 + fg * 8];
                const frag_ab v1 = *(const frag_ab*)&V_t[(16 + fr) * 136 + kc * 32 + fg * 8];
                o0[s] = __builtin_amdgcn_mfma_f32_16x16x32_bf16(v0, pf, o0[s], 0, 0, 0);
                o1[s] = __builtin_amdgcn_mfma_f32_16x16x32_bf16(v1, pf, o1[s], 0, 0, 0);
            }
        }
    }
    #pragma unroll
    for (int s = 0; s < 4; ++s) {
        const float inv = 1.0f / l[s];
        ushortT* ob = &Ob[qtok[s] * C_DIM + h * DH];
        uint2 w0, w1;
        w0.x = packbf(o0[s][0] * inv, o0[s][1] * inv);
        w0.y = packbf(o0[s][2] * inv, o0[s][3] * inv);
        w1.x = packbf(o1[s][0] * inv, o1[s][1] * inv);
        w1.y = packbf(o1[s][2] * inv, o1[s][3] * inv);
        *(uint2*)&ob[fg * 4] = w0;
        *(uint2*)&ob[16 + fg * 4] = w1;
    }
}

// ---------------- attn pass 1 (S=64): single-shot softmax per wave ----------------
template<int S, int LDK, int LDV, int LDP>
__device__ __forceinline__ void attn_wave_work(
        const ushortT* __restrict__ QKb, ushortT* __restrict__ Ob,
        const ushortT* __restrict__ K_lds, const ushortT* __restrict__ V_t,
        ushortT* __restrict__ P_lds,
        int base, int seqStride, int head, int q0base) {
    constexpr int NKT = S / 16;
    constexpr int NKC = S / 32;
    const int lane = threadIdx.x & 63;
    const int fr = lane & 15;
    const int fg = lane >> 4;
    const float scale = 0.17677669529663687f;
    #pragma unroll
    for (int s = 0; s < 4; ++s) {
        const int qq = q0base + s * 16 + fr;
        const size_t qtok = (size_t)(base + qq * seqStride);
        const frag_ab qf = *(const frag_ab*)&QKb[qtok * 512 + head * DH + fg * 8];
        f32x4 sc[NKT];
        #pragma unroll
        for (int kt = 0; kt < NKT; ++kt) {
            const frag_ab kf = *(const frag_ab*)&K_lds[(kt * 16 + fr) * LDK + fg * 8];
            sc[kt] = __builtin_amdgcn_mfma_f32_16x16x32_bf16(kf, qf, (f32x4){0.f, 0.f, 0.f, 0.f}, 0, 0, 0);
        }
        float mx = -1e30f;
        #pragma unroll
        for (int kt = 0; kt < NKT; ++kt)
            mx = fmaxf(mx, fmaxf(fmaxf(sc[kt][0], sc[kt][1]), fmaxf(sc[kt][2], sc[kt][3])));
        mx = fmaxf(mx, __shfl_xor(mx, 16, 64));
        mx = fmaxf(mx, __shfl_xor(mx, 32, 64));
        float lsum = 0.f;
        #pragma unroll
        for (int kt = 0; kt < NKT; ++kt) {
            const float p0 = __expf((sc[kt][0] - mx) * scale);
            const float p1 = __expf((sc[kt][1] - mx) * scale);
            const float p2 = __expf((sc[kt][2] - mx) * scale);
            const float p3 = __expf((sc[kt][3] - mx) * scale);
            lsum += (p0 + p1) + (p2 + p3);
            uint2 pk;
            pk.x = packbf(p0, p1);
            pk.y = packbf(p2, p3);
            *(uint2*)&P_lds[fr * LDP + kt * 16 + fg * 4] = pk;
        }
        lsum += __shfl_xor(lsum, 16, 64);
        lsum += __shfl_xor(lsum, 32, 64);
        f32x4 o0 = {0.f, 0.f, 0.f, 0.f}, o1 = {0.f, 0.f, 0.f, 0.f};
        #pragma unroll
        for (int kc = 0; kc < NKC; ++kc) {
            const frag_ab pf = *(const frag_ab*)&P_lds[fr * LDP + kc * 32 + fg * 8];
            const frag_ab v0 = *(const frag_ab*)&V_t[fr * LDV + kc * 32 + fg * 8];
            const frag_ab v1 = *(const frag_ab*)&V_t[(16 + fr) * LDV + kc * 32 + fg * 8];
            o0 = __builtin_amdgcn_mfma_f32_16x16x32_bf16(v0, pf, o0, 0, 0, 0);
            o1 = __builtin_amdgcn_mfma_f32_16x16x32_bf16(v1, pf, o1, 0, 0, 0);
        }
        const float inv = 1.0f / lsum;
        ushortT* ob = &Ob[qtok * C_DIM + head * DH];
        uint2 w0, w1;
        w0.x = packbf(o0[0] * inv, o0[1] * inv);
        w0.y = packbf(o0[2] * inv, o0[3] * inv);
        w1.x = packbf(o1[0] * inv, o1[1] * inv);
        w1.y = packbf(o1[2] * inv, o1[3] * inv);
        *(uint2*)&ob[fg * 4] = w0;
        *(uint2*)&ob[16 + fg * 4] = w1;
    }
}

__global__ __launch_bounds__(256) void attn_p1(const ushortT* __restrict__ QKb,
                                               const ushortT* __restrict__ Vb,
                                               ushortT* __restrict__ Ob) {
    __shared__ ushortT K_lds[4][64 * 40];
    __shared__ ushortT V_t[4][32 * 72];
    __shared__ ushortT P_lds[4][16 * 72];
    const int wave = threadIdx.x >> 6;
    const int lane = threadIdx.x & 63;
    const int unit = blockIdx.x * 4 + wave;
    const int h = unit & 7;
    const int g = unit >> 3;
    const int base = (g >> 8) * PETOK + (g & 255);
    #pragma unroll
    for (int it = 0; it < 4; ++it) {
        const int idx = it * 64 + lane;
        const int row = idx >> 2, ch = idx & 3;
        const size_t tok = (size_t)(base + row * 256);
        const uint4 kv = *(const uint4*)&QKb[tok * 512 + 256 + h * DH + ch * 8];
        *(uint4*)&K_lds[wave][row * 40 + ch * 8] = kv;
        const uint4 vv = *(const uint4*)&Vb[tok * C_DIM + h * DH + ch * 8];
        const ushortT* vp = (const ushortT*)&vv;
        #pragma unroll
        for (int e = 0; e < 8; ++e) V_t[wave][(ch * 8 + e) * 72 + row] = vp[e];
    }
    attn_wave_work<64, 40, 72, 72>(QKb, Ob, K_lds[wave], V_t[wave], P_lds[wave], base, 256, h, 0);
}

// ---------------- residual + LayerNorm ----------------
__global__ __launch_bounds__(256) void ln_kernel(float* __restrict__ X, const ushortT* __restrict__ Y,
                                                 const float* __restrict__ g, const float* __restrict__ be,
                                                 ushortT* __restrict__ Xb) {
    int tok = blockIdx.x * 4 + (threadIdx.x >> 6);
    int lane = threadIdx.x & 63;
    float4 x = *(float4*)&X[(size_t)tok * C_DIM + lane * 4];
    const uint2 yu = *(const uint2*)&Y[(size_t)tok * C_DIM + lane * 4];
    float v0 = x.x + bflo(yu.x), v1 = x.y + bfhi(yu.x);
    float v2 = x.z + bflo(yu.y), v3 = x.w + bfhi(yu.y);
    float s = v0 + v1 + v2 + v3;
    float ss = v0 * v0 + v1 * v1 + v2 * v2 + v3 * v3;
    #pragma unroll
    for (int off = 32; off; off >>= 1) {
        s += __shfl_xor(s, off, 64);
        ss += __shfl_xor(ss, off, 64);
    }
    float mean = s * (1.0f / 256.0f);
    float var = ss * (1.0f / 256.0f) - mean * mean;
    float inv = rsqrtf(var + LN_EPS);
    const float4 gv = *(const float4*)&g[lane * 4];
    const float4 bv = *(const float4*)&be[lane * 4];
    float o0 = (v0 - mean) * inv * gv.x + bv.x;
    float o1 = (v1 - mean) * inv * gv.y + bv.y;
    float o2 = (v2 - mean) * inv * gv.z + bv.z;
    float o3 = (v3 - mean) * inv * gv.w + bv.w;
    float4 of = {o0, o1, o2, o3};
    *(float4*)&X[(size_t)tok * C_DIM + lane * 4] = of;
    uint2 ob = {packbf(o0, o1), packbf(o2, o3)};
    *(uint2*)&Xb[(size_t)tok * C_DIM + lane * 4] = ob;
}

// ---------------- defe mask: parallel maxpool ----------------
__global__ void mask_kernel(const float* __restrict__ defe, float* __restrict__ out) {
    __shared__ float wmax[4];
    const int idx = blockIdx.x;          // 0..127
    const int b = idx >> 6;
    const int ii = (idx >> 3) & 7;
    const int jj = idx & 7;
    const int t = threadIdx.x;
    const int y = t >> 4, xx = t & 15;
    float v = defe[b * 16384 + (ii * 16 + y) * 128 + jj * 16 + xx];
    #pragma unroll
    for (int off = 32; off; off >>= 1) v = fmaxf(v, __shfl_xor(v, off, 64));
    if ((t & 63) == 0) wmax[t >> 6] = v;
    __syncthreads();
    if (t == 0) {
        float mx = fmaxf(fmaxf(wmax[0], wmax[1]), fmaxf(wmax[2], wmax[3]));
        out[8388608 + idx] = (mx > 0.0f) ? 1.0f : 0.0f;
    }
}

extern "C" void kernel_launch(void* const* d_in, const int* in_sizes, int n_in,
                              void* d_out, int out_size, void* d_ws, size_t ws_size,
                              hipStream_t stream) {
    const float* backbone = (const float*)d_in[0];
    const float* defe     = (const float*)d_in[1];
    const float* glob     = (const float*)d_in[2];
    const float* Wqkv     = (const float*)d_in[3];
    const float* bqkv     = (const float*)d_in[4];
    const float* Wo       = (const float*)d_in[5];
    const float* bo       = (const float*)d_in[6];
    const float* W1       = (const float*)d_in[7];
    const float* b1       = (const float*)d_in[8];
    const float* W2       = (const float*)d_in[9];
    const float* b2       = (const float*)d_in[10];
    const float* g1       = (const float*)d_in[11];
    const float* be1      = (const float*)d_in[12];
    const float* g2       = (const float*)d_in[13];
    const float* be2      = (const float*)d_in[14];
    const float* relW1    = (const float*)d_in[15];
    const float* relb1    = (const float*)d_in[16];
    const float* relW2    = (const float*)d_in[17];
    const float* relb2    = (const float*)d_in[18];

    // workspace layout
    ushortT* peb    = (ushortT*)d_ws;                       //  4,194,304
    ushortT* Wqkv_b = peb + 4194304;                        //    196,608
    ushortT* Wo_b   = Wqkv_b + 196608;                      //     65,536
    ushortT* W1_b   = Wo_b + 65536;                         //    262,144
    ushortT* W2_b   = W1_b + 262144;                        //    262,144
    ushortT* Xb     = W2_b + 262144;                        //  8,388,608
    ushortT* QKb    = Xb + 8388608;                         // 16,777,216
    ushortT* Vb     = QKb + 16777216;                       //  8,388,608
    ushortT* Ob     = Vb + 8388608;                         //  8,388,608
    ushortT* Hb     = QKb;                                  // FFN hidden aliases QK|V|O
    ushortT* Yb     = Ob + 8388608;                         //  8,388,608
    float*   Xf     = (float*)(Yb + 8388608);               //  8,388,608 floats
    float*   relf   = Xf + 8388608;                         //     65,536 floats
    size_t needed = (size_t)((char*)(relf + 65536) - (char*)d_ws);
    if (ws_size < needed) return;

    cvt_all_kernel<<<768, 256, 0, stream>>>(Wqkv, Wo, W1, W2, Wqkv_b);
    rel_kernel<<<256, 256, 0, stream>>>(relW1, relb1, relW2, relb2, relf);
    pe_kernel<<<dim3(128, 8), 256, 0, stream>>>(glob, relf, peb);
    window_kernel<<<dim3(128, 8, 2), 256, 0, stream>>>(backbone, Xf, Xb);

    for (int pass = 0; pass < 2; ++pass) {
        gemm_bf16<true, false><<<dim3(512 / BN, NTOK / BM), 256, 0, stream>>>(
            Xb, C_DIM, peb, Wqkv_b, bqkv, QKb, 512, C_DIM);
        gemm_bf16<false, false><<<dim3(256 / BN, NTOK / BM), 256, 0, stream>>>(
            Xb, C_DIM, nullptr, Wqkv_b + 512 * 256, bqkv + 512, Vb, C_DIM, C_DIM);
        if (pass == 0) {
            attn_p0<<<128 * NHEAD, 256, 0, stream>>>(QKb, Vb, Ob);
        } else {
            attn_p1<<<4096 / 4, 256, 0, stream>>>(QKb, Vb, Ob);
        }
        gemm_bf16<false, false><<<dim3(256 / BN, NTOK / BM), 256, 0, stream>>>(
            Ob, C_DIM, nullptr, Wo_b, bo, Yb, C_DIM, C_DIM);
        ln_kernel<<<NTOK / 4, 256, 0, stream>>>(Xf, Yb, g1, be1, Xb);
        gemm_bf16<false, true><<<dim3(DFF_DIM / BN, NTOK / BM), 256, 0, stream>>>(
            Xb, C_DIM, nullptr, W1_b, b1, Hb, DFF_DIM, C_DIM);
        gemm_bf16<false, false><<<dim3(256 / BN, NTOK / BM), 256, 0, stream>>>(
            Hb, DFF_DIM, nullptr, W2_b, b2, Yb, C_DIM, DFF_DIM);
        ln_kernel<<<NTOK / 4, 256, 0, stream>>>(Xf, Yb, g2, be2, Xb);
    }

    scatter_kernel<<<dim3(128, 8, 2), 256, 0, stream>>>(backbone, Xf, (float*)d_out);
    mask_kernel<<<128, 256, 0, stream>>>(defe, (float*)d_out);
}